// Round 1
// 2575.940 us; speedup vs baseline: 1.0021x; 1.0021x over previous
//
#include <hip/hip_runtime.h>

// GPFA e-step posterior mean on MI355X — direct Kronecker-sum solve, fp32 chains.
// M = Kbar (x) I_F + I_T (x) A,  Kbar = sum_f inv(K_f),  A = C'R^-1 C = V Lam V'.
// Per factor-eigenpair i: (Kbar + lam_i I) xt_i = bt_i  (512x512, 128 RHS).
// GJ chains: one apply-kernel per step (pure tile GEMMs, pivot inverse read from
// global); the NEXT step's 64x64 pivot inversion is fused into the single
// designated block that produces tile (k+1,k+1). fp32 eig8 (hardware rcp/rsqrt).
//
// R1: eig8_kernel p/q loops fully unrolled -> all A/V indices compile-time ->
// arrays promoted from scratch to VGPRs (was 155 us of serial scratch latency).

#define NF 8
#define TBINS 512
#define NNEU 512
#define NTRI 128
#define PAD 68

// ---- ws layout (float offsets) ----
#define OFF_A0     0                 // float[8*512*512] ping
#define OFF_A1     2097152           // float[8*512*512] pong
#define OFF_CRVT   4194304           // float[512*8]
#define OFF_CRVVT  4198400           // float[512*8]
#define OFF_CCT    4202496           // float[64]
#define OFF_CD     4202560           // float[64]
#define OFF_CDV    4202624           // float[64]
#define OFF_RINV   4202688           // float[512]
#define OFF_LAM    4203200           // float[8]
#define OFF_VF     4203216           // float[64]
#define OFF_BT     4203280           // float[4096*128]
#define OFF_XT     4727568           // float[4096*128]
#define OFF_PP0    5251856           // float[8*4096] pivot-inverse buf A
#define OFF_PP1    5284624           // float[8*4096] pivot-inverse buf B

__device__ __forceinline__ void load8(float* v, const float* ptr){
  float4 a = ((const float4*)ptr)[0];
  float4 b = ((const float4*)ptr)[1];
  v[0]=a.x; v[1]=a.y; v[2]=a.z; v[3]=a.w;
  v[4]=b.x; v[5]=b.y; v[6]=b.z; v[7]=b.w;
}
__device__ __forceinline__ void store8(float* ptr, const float* v){
  ((float4*)ptr)[0] = make_float4(v[0],v[1],v[2],v[3]);
  ((float4*)ptr)[1] = make_float4(v[4],v[5],v[6],v[7]);
}

// in-place GJ inversion of 64x64 LDS tile P (SPD, no pivoting); 256 threads
__device__ __forceinline__ void gj_invert64(float* P, float* colk, float* rowk, int tid){
  int j = tid & 63, ig = tid >> 6;
  for (int kk = 0; kk < 64; ++kk){
    if (tid < 64) colk[tid] = P[tid*PAD + kk];
    else if (tid < 128) rowk[tid-64] = P[kk*PAD + (tid-64)];
    __syncthreads();
    float pinv = 1.0f / colk[kk];
    if (j == kk){
      #pragma unroll
      for (int m = 0; m < 16; ++m){
        int i = ig*16 + m;
        P[i*PAD + kk] = (i == kk) ? pinv : (-colk[i] * pinv);
      }
    } else {
      float newr = rowk[j] * pinv;
      #pragma unroll
      for (int m = 0; m < 16; ++m){
        int i = ig*16 + m;
        if (i == kk) P[kk*PAD + j] = newr;
        else P[i*PAD + j] -= colk[i] * newr;
      }
    }
    __syncthreads();
  }
}

// ---------------- prep ----------------
__global__ void prep_kernel(const float* __restrict__ Cm, const float* __restrict__ dm,
                            const float* __restrict__ r_diag,
                            float* __restrict__ crvT, float* __restrict__ ccT,
                            float* __restrict__ cd, float* __restrict__ rinv){
  __shared__ float s_crv[NNEU*NF];
  __shared__ float s_cm[NNEU*NF];
  __shared__ float s_dm[NNEU];
  int tid = threadIdx.x;            // 512; thread == neuron n
  float ri = 1.0f / r_diag[tid];
  rinv[tid] = ri;
  s_dm[tid] = dm[tid];
  #pragma unroll
  for (int f = 0; f < NF; ++f){
    float cv = Cm[tid*NF + f];
    s_cm[tid*NF + f] = cv;
    float v = cv * ri;
    s_crv[tid*NF + f] = v;
    crvT[tid*NF + f] = v;
  }
  __syncthreads();
  if (tid < 64){
    int f = tid >> 3, g = tid & 7;
    float acc = 0.f;
    for (int n = 0; n < NNEU; ++n) acc += s_crv[n*NF+f] * s_cm[n*NF+g];
    ccT[tid] = acc;
  } else if (tid < 72){
    int f = tid - 64;
    float acc = 0.f;
    for (int n = 0; n < NNEU; ++n) acc += s_crv[n*NF+f] * s_dm[n];
    cd[f] = acc;
  }
}

// ---------------- 8x8 eig: cyclic Jacobi, fp32, algebraic rotations ----------------
// p/q loops fully unrolled so every A[][]/V[][] index is compile-time constant:
// SROA keeps both 8x8 arrays in VGPRs (runtime p,q forced them to scratch; that
// single-lane scratch latency chain was the longest dispatch at ~155 us).
__global__ void eig8_kernel(const float* __restrict__ ccT,
                            float* __restrict__ Vf, float* __restrict__ lam){
  if (threadIdx.x != 0) return;
  float A[8][8], V[8][8];
  #pragma unroll
  for (int a = 0; a < 8; ++a)
    #pragma unroll
    for (int b = 0; b < 8; ++b){
      A[a][b] = ccT[a*8+b];
      V[a][b] = (a == b) ? 1.0f : 0.0f;
    }
  for (int sw = 0; sw < 8; ++sw){
    #pragma unroll
    for (int p = 0; p < 7; ++p){
      #pragma unroll
      for (int q = p+1; q < 8; ++q){
        float apq = A[p][q];
        if (fabsf(apq) < 1e-20f) continue;
        float beta = (A[q][q] - A[p][p]) / (2.0f * apq);
        float tt = ((beta >= 0.0f) ? 1.0f : -1.0f) / (fabsf(beta) + sqrtf(1.0f + beta*beta));
        float c = 1.0f / sqrtf(1.0f + tt*tt);
        float s = tt * c;
        #pragma unroll
        for (int kk = 0; kk < 8; ++kk){
          float akp = A[kk][p], akq = A[kk][q];
          A[kk][p] = c*akp - s*akq;
          A[kk][q] = s*akp + c*akq;
        }
        #pragma unroll
        for (int kk = 0; kk < 8; ++kk){
          float apk = A[p][kk], aqk = A[q][kk];
          A[p][kk] = c*apk - s*aqk;
          A[q][kk] = s*apk + c*aqk;
        }
        #pragma unroll
        for (int kk = 0; kk < 8; ++kk){
          float vkp = V[kk][p], vkq = V[kk][q];
          V[kk][p] = c*vkp - s*vkq;
          V[kk][q] = s*vkp + c*vkq;
        }
      }
    }
  }
  #pragma unroll
  for (int i = 0; i < 8; ++i) lam[i] = A[i][i];
  #pragma unroll
  for (int a = 0; a < 8; ++a)
    #pragma unroll
    for (int b = 0; b < 8; ++b) Vf[a*8+b] = V[a][b];
}

// ---------------- rotate crv, cd by V^T ----------------
__global__ void rotv_kernel(const float* __restrict__ crvT, const float* __restrict__ cd,
                            const float* __restrict__ Vf,
                            float* __restrict__ crvVT, float* __restrict__ cdV){
  __shared__ float Vl[64];
  int tid = threadIdx.x;   // 512
  if (tid < 64) Vl[tid] = Vf[tid];
  __syncthreads();
  float cv[8], ov[8];
  load8(cv, crvT + tid*8);
  #pragma unroll
  for (int i = 0; i < 8; ++i){
    float s = 0.f;
    #pragma unroll
    for (int f = 0; f < 8; ++f) s += Vl[f*8+i] * cv[f];
    ov[i] = s;
  }
  store8(crvVT + tid*8, ov);
  if (tid < 8){
    float s = 0.f;
    #pragma unroll
    for (int f = 0; f < 8; ++f) s += Vl[f*8+tid] * cd[f];
    cdV[tid] = s;
  }
}

// ---------------- build K_f (fp32) ----------------
__global__ void buildK_kernel(const float* __restrict__ gamma, float* __restrict__ A0){
  int f = blockIdx.y;
  int idx = blockIdx.x*256 + threadIdx.x;   // t*512+u
  int t = idx >> 9, u = idx & 511;
  float g = gamma[f];
  float d = (float)(t - u);
  float v = 0.999f * expf(-0.5f * g * d * d);
  if (t == u) v += 1.0e-3f;
  A0[(size_t)f*TBINS*TBINS + idx] = v;
}

// ---------------- G_i = (sum_f Kinv_f) + lam_i I ----------------
__global__ void buildG_kernel(const float* __restrict__ A0, const float* __restrict__ lam,
                              float* __restrict__ A1){
  int idx = blockIdx.x*256 + threadIdx.x;       // 0..262143
  float s = 0.f;
  #pragma unroll
  for (int f2 = 0; f2 < NF; ++f2) s += A0[(size_t)f2*TBINS*TBINS + idx];
  bool diag = ((idx >> 9) == (idx & 511));
  #pragma unroll
  for (int i = 0; i < NF; ++i)
    A1[(size_t)i*TBINS*TBINS + idx] = s + (diag ? lam[i] : 0.f);
}

// ---------------- standalone pivot inversion (chain head): Pout = inv(A[f][0:64][0:64]) ----------------
__global__ __launch_bounds__(256) void gj_pivot0(const float* __restrict__ A,
                                                 float* __restrict__ Pout){
  __shared__ float P[64*PAD];
  __shared__ float colk[64];
  __shared__ float rowk[64];
  int f = blockIdx.x;
  int tid = threadIdx.x;
  const float* Af = A + (size_t)f*TBINS*TBINS;
  for (int v = tid; v < 1024; v += 256){
    int r = v >> 4, c4 = (v & 15) << 2;
    *(float4*)&P[r*PAD + c4] = *(const float4*)(Af + (size_t)r*TBINS + c4);
  }
  __syncthreads();
  gj_invert64(P, colk, rowk, tid);
  for (int v = tid; v < 1024; v += 256){
    int r = v >> 4, c4 = (v & 15) << 2;
    *(float4*)(Pout + f*4096 + r*64 + c4) = *(float4*)&P[r*PAD + c4];
  }
}

// ---------------- GJ apply step: src -> dst; pivot inverse from Pin; designated
// block (k+1,k+1) also inverts its output tile -> Pout ----------------
#define ACC4(tm, fm) \
  tm[0] += fm.x*s0.x + fm.y*s1.x + fm.z*s2.x + fm.w*s3.x; \
  tm[1] += fm.x*s0.y + fm.y*s1.y + fm.z*s2.y + fm.w*s3.y; \
  tm[2] += fm.x*s0.z + fm.y*s1.z + fm.z*s2.z + fm.w*s3.z; \
  tm[3] += fm.x*s0.w + fm.y*s1.w + fm.z*s2.w + fm.w*s3.w;

__global__ __launch_bounds__(256) void gj_apply(const float* __restrict__ src,
                                                float* __restrict__ dst,
                                                const float* __restrict__ Pin,
                                                float* __restrict__ Pout,
                                                int k, int inv_next){
  __shared__ float P[64*PAD];
  __shared__ float Q[64*PAD];
  __shared__ float F[64*PAD];
  __shared__ float colk[64];
  __shared__ float rowk[64];
  int f  = blockIdx.y;
  int ti = blockIdx.x >> 3, tj = blockIdx.x & 7;
  int tid = threadIdx.x;
  const float* A = src + (size_t)f*TBINS*TBINS;
  float* D = dst + (size_t)f*TBINS*TBINS;

  // load pivot inverse (precomputed)
  for (int v = tid; v < 1024; v += 256){
    int r = v >> 4, c4 = (v & 15) << 2;
    *(float4*)&P[r*PAD + c4] = *(const float4*)(Pin + f*4096 + r*64 + c4);
  }
  if (tj != k){
    for (int v = tid; v < 1024; v += 256){
      int r = v >> 4, c4 = (v & 15) << 2;
      *(float4*)&Q[r*PAD + c4] = *(const float4*)(A + (size_t)(k*64+r)*TBINS + tj*64 + c4);
    }
  }
  if (ti != k){
    for (int v = tid; v < 1024; v += 256){
      int r = v >> 4, c4 = (v & 15) << 2;
      *(float4*)&F[r*PAD + c4] = *(const float4*)(A + (size_t)(ti*64+r)*TBINS + k*64 + c4);
    }
  }
  __syncthreads();

  int jg = (tid & 15) << 2;   // output cols jg..jg+3
  int ib = (tid >> 4) << 2;   // output rows ib..ib+3

  if (tj == k){
    if (ti == k){
      // pass-through: D[k][k] = P
      for (int v = tid; v < 1024; v += 256){
        int r = v >> 4, c4 = (v & 15) << 2;
        *(float4*)(D + (size_t)(k*64+r)*TBINS + k*64 + c4) = *(float4*)&P[r*PAD + c4];
      }
      return;
    }
    // D = -F @ P
    float w[4][4] = {{0.f,0.f,0.f,0.f},{0.f,0.f,0.f,0.f},{0.f,0.f,0.f,0.f},{0.f,0.f,0.f,0.f}};
    for (int u4 = 0; u4 < 64; u4 += 4){
      float4 f0 = *(float4*)&F[(ib+0)*PAD + u4];
      float4 f1 = *(float4*)&F[(ib+1)*PAD + u4];
      float4 f2 = *(float4*)&F[(ib+2)*PAD + u4];
      float4 f3 = *(float4*)&F[(ib+3)*PAD + u4];
      float4 s0 = *(float4*)&P[(u4+0)*PAD + jg];
      float4 s1 = *(float4*)&P[(u4+1)*PAD + jg];
      float4 s2 = *(float4*)&P[(u4+2)*PAD + jg];
      float4 s3 = *(float4*)&P[(u4+3)*PAD + jg];
      ACC4(w[0], f0); ACC4(w[1], f1); ACC4(w[2], f2); ACC4(w[3], f3);
    }
    #pragma unroll
    for (int m = 0; m < 4; ++m)
      *(float4*)(D + (size_t)(ti*64+ib+m)*TBINS + k*64 + jg)
        = make_float4(-w[m][0], -w[m][1], -w[m][2], -w[m][3]);
    return;
  }

  // tj != k: T = P @ Q (P symmetric: P'[ib][u] = P[u][ib])
  float t[4][4] = {{0.f,0.f,0.f,0.f},{0.f,0.f,0.f,0.f},{0.f,0.f,0.f,0.f},{0.f,0.f,0.f,0.f}};
  for (int u = 0; u < 64; ++u){
    float4 pv = *(float4*)&P[u*PAD + ib];
    float4 qv = *(float4*)&Q[u*PAD + jg];
    t[0][0]+=pv.x*qv.x; t[0][1]+=pv.x*qv.y; t[0][2]+=pv.x*qv.z; t[0][3]+=pv.x*qv.w;
    t[1][0]+=pv.y*qv.x; t[1][1]+=pv.y*qv.y; t[1][2]+=pv.y*qv.z; t[1][3]+=pv.y*qv.w;
    t[2][0]+=pv.z*qv.x; t[2][1]+=pv.z*qv.y; t[2][2]+=pv.z*qv.z; t[2][3]+=pv.z*qv.w;
    t[3][0]+=pv.w*qv.x; t[3][1]+=pv.w*qv.y; t[3][2]+=pv.w*qv.z; t[3][3]+=pv.w*qv.w;
  }
  if (ti == k){
    // D = T directly from registers
    #pragma unroll
    for (int m = 0; m < 4; ++m)
      *(float4*)(D + (size_t)(k*64+ib+m)*TBINS + tj*64 + jg)
        = make_float4(t[m][0],t[m][1],t[m][2],t[m][3]);
    return;
  }
  __syncthreads();               // all reads of Q done
  #pragma unroll
  for (int m = 0; m < 4; ++m)
    *(float4*)&Q[(ib+m)*PAD + jg] = make_float4(t[m][0],t[m][1],t[m][2],t[m][3]);
  __syncthreads();               // T visible to all

  // Schur: D = A[ti][tj] - F @ T
  float w[4][4] = {{0.f,0.f,0.f,0.f},{0.f,0.f,0.f,0.f},{0.f,0.f,0.f,0.f},{0.f,0.f,0.f,0.f}};
  for (int u4 = 0; u4 < 64; u4 += 4){
    float4 f0 = *(float4*)&F[(ib+0)*PAD + u4];
    float4 f1 = *(float4*)&F[(ib+1)*PAD + u4];
    float4 f2 = *(float4*)&F[(ib+2)*PAD + u4];
    float4 f3 = *(float4*)&F[(ib+3)*PAD + u4];
    float4 s0 = *(float4*)&Q[(u4+0)*PAD + jg];
    float4 s1 = *(float4*)&Q[(u4+1)*PAD + jg];
    float4 s2 = *(float4*)&Q[(u4+2)*PAD + jg];
    float4 s3 = *(float4*)&Q[(u4+3)*PAD + jg];
    ACC4(w[0], f0); ACC4(w[1], f1); ACC4(w[2], f2); ACC4(w[3], f3);
  }
  #pragma unroll
  for (int m = 0; m < 4; ++m){
    float4 av = *(const float4*)(A + (size_t)(ti*64+ib+m)*TBINS + tj*64 + jg);
    float4 dv = make_float4(av.x - w[m][0], av.y - w[m][1], av.z - w[m][2], av.w - w[m][3]);
    *(float4*)(D + (size_t)(ti*64+ib+m)*TBINS + tj*64 + jg) = dv;
    w[m][0] = dv.x; w[m][1] = dv.y; w[m][2] = dv.z; w[m][3] = dv.w;
  }

  // designated block also inverts its tile -> next step's pivot inverse
  if (inv_next && ti == k+1 && tj == k+1){
    __syncthreads();
    #pragma unroll
    for (int m = 0; m < 4; ++m)
      *(float4*)&P[(ib+m)*PAD + jg] = make_float4(w[m][0],w[m][1],w[m][2],w[m][3]);
    __syncthreads();
    gj_invert64(P, colk, rowk, tid);
    for (int v = tid; v < 1024; v += 256){
      int r = v >> 4, c4 = (v & 15) << 2;
      *(float4*)(Pout + f*4096 + r*64 + c4) = *(float4*)&P[r*PAD + c4];
    }
  }
}

// ---------------- term1: bt[(t*8+i)*128+c] = sum_n crvV[i][n] spike[c][n][t] - cdV[i] ----------------
__global__ void term1_kernel(const float* __restrict__ spike, const float* __restrict__ crvVT,
                             const float* __restrict__ cdV, float* __restrict__ bt){
  __shared__ float crl[NNEU*NF];   // [n][i]
  __shared__ float ot[128][17];
  int t0 = blockIdx.x * 16;
  int c0 = blockIdx.y * 16;
  int tid = threadIdx.x;           // 256
  int tl = tid & 15, cl = tid >> 4;
  for (int n2 = tid; n2 < NNEU*NF; n2 += 256) crl[n2] = crvVT[n2];
  __syncthreads();
  float acc[8] = {0.f,0.f,0.f,0.f,0.f,0.f,0.f,0.f};
  const float* Sp = spike + (size_t)(c0+cl)*NNEU*TBINS + t0 + tl;
  for (int n = 0; n < NNEU; n += 4){
    float s0 = Sp[(size_t)(n+0)*TBINS];
    float s1 = Sp[(size_t)(n+1)*TBINS];
    float s2 = Sp[(size_t)(n+2)*TBINS];
    float s3 = Sp[(size_t)(n+3)*TBINS];
    #pragma unroll
    for (int i = 0; i < 8; ++i)
      acc[i] += crl[(n+0)*8+i]*s0 + crl[(n+1)*8+i]*s1 + crl[(n+2)*8+i]*s2 + crl[(n+3)*8+i]*s3;
  }
  #pragma unroll
  for (int i = 0; i < 8; ++i) ot[tl*8+i][cl] = acc[i] - cdV[i];
  __syncthreads();
  int row = tid >> 1, off = (tid & 1) * 8;    // row = tlocal*8+i
  int tt = t0 + (row >> 3), ii = row & 7;
  float* dst = bt + (size_t)(tt*8+ii)*NTRI + c0 + off;
  #pragma unroll
  for (int k = 0; k < 8; ++k) dst[k] = ot[row][off+k];
}

// ---------------- batched GEMM: xt_i = H_i (512x512) @ bt_i (512x128) ----------------
__global__ void gemm_kernel(const float* __restrict__ H, const float* __restrict__ bt,
                            float* __restrict__ xt){
  __shared__ float Ht[32][68];
  __shared__ float Bt[64][128];
  int i  = blockIdx.y;
  int t0 = blockIdx.x * 32;
  int tid = threadIdx.x;           // 256
  int gt = tid >> 5;               // 0..7
  int gc = tid & 31;               // 0..31
  float acc[4][4] = {{0.f,0.f,0.f,0.f},{0.f,0.f,0.f,0.f},{0.f,0.f,0.f,0.f},{0.f,0.f,0.f,0.f}};
  const float* Hi = H + (size_t)i*TBINS*TBINS;
  for (int uc = 0; uc < 8; ++uc){
    int u0 = uc*64;
    __syncthreads();
    for (int v = tid; v < 512; v += 256){
      int r = v >> 4, c4 = (v & 15) << 2;
      *(float4*)&Ht[r][c4] = *(const float4*)(Hi + (size_t)(t0+r)*TBINS + u0 + c4);
    }
    for (int v = tid; v < 2048; v += 256){
      int r = v >> 5, c4 = (v & 31) << 2;
      *(float4*)&Bt[r][c4] = *(const float4*)(bt + (size_t)((u0+r)*8 + i)*NTRI + c4);
    }
    __syncthreads();
    for (int u = 0; u < 64; ++u){
      float h0 = Ht[gt*4+0][u], h1 = Ht[gt*4+1][u], h2 = Ht[gt*4+2][u], h3 = Ht[gt*4+3][u];
      float b0 = Bt[u][gc], b1 = Bt[u][gc+32], b2 = Bt[u][gc+64], b3 = Bt[u][gc+96];
      acc[0][0] += h0*b0; acc[0][1] += h0*b1; acc[0][2] += h0*b2; acc[0][3] += h0*b3;
      acc[1][0] += h1*b0; acc[1][1] += h1*b1; acc[1][2] += h1*b2; acc[1][3] += h1*b3;
      acc[2][0] += h2*b0; acc[2][1] += h2*b1; acc[2][2] += h2*b2; acc[2][3] += h2*b3;
      acc[3][0] += h3*b0; acc[3][1] += h3*b1; acc[3][2] += h3*b2; acc[3][3] += h3*b3;
    }
  }
  #pragma unroll
  for (int m = 0; m < 4; ++m)
    #pragma unroll
    for (int j = 0; j < 4; ++j)
      xt[(size_t)((t0 + gt*4 + m)*8 + i)*NTRI + gc + 32*j] = acc[m][j];
}

// ---------------- output: out[c][f][t] = sum_i V[f][i] xt[(t*8+i)*128+c] ----------------
__global__ void output_kernel(const float* __restrict__ xt, const float* __restrict__ Vf,
                              float* __restrict__ out){
  __shared__ float T[128][68];
  __shared__ float Vl[64];
  int t0 = blockIdx.x * 64, c0 = blockIdx.y * 16;
  int tid = threadIdx.x;   // 256
  if (tid < 64) Vl[tid] = Vf[tid];
  __syncthreads();
  for (int idx = tid; idx < 1024; idx += 256){
    int tl = idx >> 4, cl = idx & 15;
    float xv[8];
    #pragma unroll
    for (int i = 0; i < 8; ++i)
      xv[i] = xt[(size_t)((t0+tl)*8+i)*NTRI + c0 + cl];
    #pragma unroll
    for (int f = 0; f < 8; ++f){
      float s = 0.f;
      #pragma unroll
      for (int i = 0; i < 8; ++i) s += Vl[f*8+i] * xv[i];
      T[cl*8+f][tl] = s;
    }
  }
  __syncthreads();
  int row = tid >> 1, half = tid & 1;   // row = cl*8+f
  int cc = c0 + (row >> 3), ff = row & 7;
  float* dst = out + (size_t)cc*NF*TBINS + ff*TBINS + t0 + half*32;
  #pragma unroll
  for (int k = 0; k < 8; ++k)
    ((float4*)dst)[k] = *(float4*)&T[row][half*32 + k*4];
}

extern "C" void kernel_launch(void* const* d_in, const int* in_sizes, int n_in,
                              void* d_out, int out_size, void* d_ws, size_t ws_size,
                              hipStream_t stream) {
  const float* spike  = (const float*)d_in[0];
  const float* Cm     = (const float*)d_in[1];
  const float* dm     = (const float*)d_in[2];
  const float* r_diag = (const float*)d_in[3];
  const float* gamma  = (const float*)d_in[4];
  float* out = (float*)d_out;
  float* ws = (float*)d_ws;

  float*  A0    = ws + OFF_A0;
  float*  A1    = ws + OFF_A1;
  float*  crvT  = ws + OFF_CRVT;
  float*  crvVT = ws + OFF_CRVVT;
  float*  ccT   = ws + OFF_CCT;
  float*  cd    = ws + OFF_CD;
  float*  cdV   = ws + OFF_CDV;
  float*  rinv  = ws + OFF_RINV;
  float*  lam   = ws + OFF_LAM;
  float*  Vf    = ws + OFF_VF;
  float*  bt    = ws + OFF_BT;
  float*  xt    = ws + OFF_XT;
  float*  Pb[2] = { ws + OFF_PP0, ws + OFF_PP1 };

  prep_kernel<<<1, 512, 0, stream>>>(Cm, dm, r_diag, crvT, ccT, cd, rinv);
  eig8_kernel<<<1, 64, 0, stream>>>(ccT, Vf, lam);
  rotv_kernel<<<1, 512, 0, stream>>>(crvT, cd, Vf, crvVT, cdV);
  buildK_kernel<<<dim3(1024, 8), 256, 0, stream>>>(gamma, A0);

  // chain 1: invert K_f (ping-pong A0 <-> A1, 8 steps -> result in A0)
  gj_pivot0<<<8, 256, 0, stream>>>(A0, Pb[0]);
  {
    float* s = A0; float* d = A1;
    for (int k = 0; k < 8; ++k){
      gj_apply<<<dim3(64, 8), 256, 0, stream>>>(s, d, Pb[k&1], Pb[(k+1)&1], k, (k < 7) ? 1 : 0);
      float* tmp = s; s = d; d = tmp;
    }
  }
  buildG_kernel<<<1024, 256, 0, stream>>>(A0, lam, A1);
  // chain 2: invert G_i (start A1, 8 steps -> H in A1)
  gj_pivot0<<<8, 256, 0, stream>>>(A1, Pb[0]);
  {
    float* s = A1; float* d = A0;
    for (int k = 0; k < 8; ++k){
      gj_apply<<<dim3(64, 8), 256, 0, stream>>>(s, d, Pb[k&1], Pb[(k+1)&1], k, (k < 7) ? 1 : 0);
      float* tmp = s; s = d; d = tmp;
    }
  }
  term1_kernel<<<dim3(32, 8), 256, 0, stream>>>(spike, crvVT, cdV, bt);
  gemm_kernel<<<dim3(16, 8), 256, 0, stream>>>(A1, bt, xt);
  output_kernel<<<dim3(8, 8), 256, 0, stream>>>(xt, Vf, out);
}

// Round 2
// 2514.482 us; speedup vs baseline: 1.0266x; 1.0244x over previous
//
#include <hip/hip_runtime.h>

// GPFA e-step posterior mean on MI355X — direct Kronecker-sum solve, fp32 chains.
// M = Kbar (x) I_F + I_T (x) A,  Kbar = sum_f inv(K_f),  A = C'R^-1 C = V Lam V'.
// Per factor-eigenpair i: (Kbar + lam_i I) xt_i = bt_i  (512x512, 128 RHS).
// GJ chains: one apply-kernel per step (pure tile GEMMs, pivot inverse read from
// global); the NEXT step's 64x64 pivot inversion is fused into the single
// designated block that produces tile (k+1,k+1). fp32 eig8 (hardware rcp/rsqrt).
//
// R2: eig8 rewritten wave-parallel — lane a*8+b holds A[a][b],V[a][b] as SCALARS
// (no arrays -> no scratch; R1's unroll failed because SROA runs before the
// unroller in LLVM's pipeline). Rotation math/order bit-identical to serial.

#define NF 8
#define TBINS 512
#define NNEU 512
#define NTRI 128
#define PAD 68

// ---- ws layout (float offsets) ----
#define OFF_A0     0                 // float[8*512*512] ping
#define OFF_A1     2097152           // float[8*512*512] pong
#define OFF_CRVT   4194304           // float[512*8]
#define OFF_CRVVT  4198400           // float[512*8]
#define OFF_CCT    4202496           // float[64]
#define OFF_CD     4202560           // float[64]
#define OFF_CDV    4202624           // float[64]
#define OFF_RINV   4202688           // float[512]
#define OFF_LAM    4203200           // float[8]
#define OFF_VF     4203216           // float[64]
#define OFF_BT     4203280           // float[4096*128]
#define OFF_XT     4727568           // float[4096*128]
#define OFF_PP0    5251856           // float[8*4096] pivot-inverse buf A
#define OFF_PP1    5284624           // float[8*4096] pivot-inverse buf B

__device__ __forceinline__ void load8(float* v, const float* ptr){
  float4 a = ((const float4*)ptr)[0];
  float4 b = ((const float4*)ptr)[1];
  v[0]=a.x; v[1]=a.y; v[2]=a.z; v[3]=a.w;
  v[4]=b.x; v[5]=b.y; v[6]=b.z; v[7]=b.w;
}
__device__ __forceinline__ void store8(float* ptr, const float* v){
  ((float4*)ptr)[0] = make_float4(v[0],v[1],v[2],v[3]);
  ((float4*)ptr)[1] = make_float4(v[4],v[5],v[6],v[7]);
}

// in-place GJ inversion of 64x64 LDS tile P (SPD, no pivoting); 256 threads
__device__ __forceinline__ void gj_invert64(float* P, float* colk, float* rowk, int tid){
  int j = tid & 63, ig = tid >> 6;
  for (int kk = 0; kk < 64; ++kk){
    if (tid < 64) colk[tid] = P[tid*PAD + kk];
    else if (tid < 128) rowk[tid-64] = P[kk*PAD + (tid-64)];
    __syncthreads();
    float pinv = 1.0f / colk[kk];
    if (j == kk){
      #pragma unroll
      for (int m = 0; m < 16; ++m){
        int i = ig*16 + m;
        P[i*PAD + kk] = (i == kk) ? pinv : (-colk[i] * pinv);
      }
    } else {
      float newr = rowk[j] * pinv;
      #pragma unroll
      for (int m = 0; m < 16; ++m){
        int i = ig*16 + m;
        if (i == kk) P[kk*PAD + j] = newr;
        else P[i*PAD + j] -= colk[i] * newr;
      }
    }
    __syncthreads();
  }
}

// ---------------- prep ----------------
__global__ void prep_kernel(const float* __restrict__ Cm, const float* __restrict__ dm,
                            const float* __restrict__ r_diag,
                            float* __restrict__ crvT, float* __restrict__ ccT,
                            float* __restrict__ cd, float* __restrict__ rinv){
  __shared__ float s_crv[NNEU*NF];
  __shared__ float s_cm[NNEU*NF];
  __shared__ float s_dm[NNEU];
  int tid = threadIdx.x;            // 512; thread == neuron n
  float ri = 1.0f / r_diag[tid];
  rinv[tid] = ri;
  s_dm[tid] = dm[tid];
  #pragma unroll
  for (int f = 0; f < NF; ++f){
    float cv = Cm[tid*NF + f];
    s_cm[tid*NF + f] = cv;
    float v = cv * ri;
    s_crv[tid*NF + f] = v;
    crvT[tid*NF + f] = v;
  }
  __syncthreads();
  if (tid < 64){
    int f = tid >> 3, g = tid & 7;
    float acc = 0.f;
    for (int n = 0; n < NNEU; ++n) acc += s_crv[n*NF+f] * s_cm[n*NF+g];
    ccT[tid] = acc;
  } else if (tid < 72){
    int f = tid - 64;
    float acc = 0.f;
    for (int n = 0; n < NNEU; ++n) acc += s_crv[n*NF+f] * s_dm[n];
    cd[f] = acc;
  }
}

// ---------------- 8x8 eig: cyclic Jacobi, wave-parallel, fp32 ----------------
// Lane a*8+b owns scalars A[a][b], V[a][b]. Rotations via __shfl; c,s computed
// redundantly on every lane from wave-broadcast apq/app/aqq (bit-identical).
// Update order matches the serial version exactly: column rotation (reads
// pre-update values — the shfl snapshots all lanes before any write), V column
// rotation, then row rotation reading the column-updated values.
__global__ void eig8_kernel(const float* __restrict__ ccT,
                            float* __restrict__ Vf, float* __restrict__ lam){
  int lane = threadIdx.x & 63;      // one wave, 64 lanes
  int a = lane >> 3, b = lane & 7;
  float Av = ccT[lane];
  float Vv = (a == b) ? 1.0f : 0.0f;
  for (int sw = 0; sw < 8; ++sw){
    for (int p = 0; p < 7; ++p){
      for (int q = p + 1; q < 8; ++q){
        float apq = __shfl(Av, p*8 + q, 64);
        if (fabsf(apq) < 1e-20f) continue;          // uniform: apq is wave-broadcast
        float app = __shfl(Av, p*8 + p, 64);
        float aqq = __shfl(Av, q*8 + q, 64);
        float beta = (aqq - app) / (2.0f * apq);
        float tt = ((beta >= 0.0f) ? 1.0f : -1.0f) / (fabsf(beta) + sqrtf(1.0f + beta*beta));
        float c = 1.0f / sqrtf(1.0f + tt*tt);
        float s = tt * c;
        // column rotation: A[:,p] = c*A[:,p]-s*A[:,q]; A[:,q] = s*A[:,p]+c*A[:,q]
        int bp = (b == p) ? q : (b == q) ? p : b;   // partner column
        float Ac = __shfl(Av, a*8 + bp, 64);        // snapshot before writes
        float Vc = __shfl(Vv, a*8 + bp, 64);
        if (b == p)      { Av = c*Av - s*Ac;  Vv = c*Vv - s*Vc; }
        else if (b == q) { Av = s*Ac + c*Av;  Vv = s*Vc + c*Vv; }
        // row rotation on column-updated A: A[p,:] = c*A[p,:]-s*A[q,:]; A[q,:] = s*A[p,:]+c*A[q,:]
        int ap = (a == p) ? q : (a == q) ? p : a;   // partner row
        float Ar = __shfl(Av, ap*8 + b, 64);
        if (a == p)      Av = c*Av - s*Ar;
        else if (a == q) Av = s*Ar + c*Av;
      }
    }
  }
  if (a == b) lam[a] = Av;
  Vf[lane] = Vv;
}

// ---------------- rotate crv, cd by V^T ----------------
__global__ void rotv_kernel(const float* __restrict__ crvT, const float* __restrict__ cd,
                            const float* __restrict__ Vf,
                            float* __restrict__ crvVT, float* __restrict__ cdV){
  __shared__ float Vl[64];
  int tid = threadIdx.x;   // 512
  if (tid < 64) Vl[tid] = Vf[tid];
  __syncthreads();
  float cv[8], ov[8];
  load8(cv, crvT + tid*8);
  #pragma unroll
  for (int i = 0; i < 8; ++i){
    float s = 0.f;
    #pragma unroll
    for (int f = 0; f < 8; ++f) s += Vl[f*8+i] * cv[f];
    ov[i] = s;
  }
  store8(crvVT + tid*8, ov);
  if (tid < 8){
    float s = 0.f;
    #pragma unroll
    for (int f = 0; f < 8; ++f) s += Vl[f*8+tid] * cd[f];
    cdV[tid] = s;
  }
}

// ---------------- build K_f (fp32) ----------------
__global__ void buildK_kernel(const float* __restrict__ gamma, float* __restrict__ A0){
  int f = blockIdx.y;
  int idx = blockIdx.x*256 + threadIdx.x;   // t*512+u
  int t = idx >> 9, u = idx & 511;
  float g = gamma[f];
  float d = (float)(t - u);
  float v = 0.999f * expf(-0.5f * g * d * d);
  if (t == u) v += 1.0e-3f;
  A0[(size_t)f*TBINS*TBINS + idx] = v;
}

// ---------------- G_i = (sum_f Kinv_f) + lam_i I ----------------
__global__ void buildG_kernel(const float* __restrict__ A0, const float* __restrict__ lam,
                              float* __restrict__ A1){
  int idx = blockIdx.x*256 + threadIdx.x;       // 0..262143
  float s = 0.f;
  #pragma unroll
  for (int f2 = 0; f2 < NF; ++f2) s += A0[(size_t)f2*TBINS*TBINS + idx];
  bool diag = ((idx >> 9) == (idx & 511));
  #pragma unroll
  for (int i = 0; i < NF; ++i)
    A1[(size_t)i*TBINS*TBINS + idx] = s + (diag ? lam[i] : 0.f);
}

// ---------------- standalone pivot inversion (chain head): Pout = inv(A[f][0:64][0:64]) ----------------
__global__ __launch_bounds__(256) void gj_pivot0(const float* __restrict__ A,
                                                 float* __restrict__ Pout){
  __shared__ float P[64*PAD];
  __shared__ float colk[64];
  __shared__ float rowk[64];
  int f = blockIdx.x;
  int tid = threadIdx.x;
  const float* Af = A + (size_t)f*TBINS*TBINS;
  for (int v = tid; v < 1024; v += 256){
    int r = v >> 4, c4 = (v & 15) << 2;
    *(float4*)&P[r*PAD + c4] = *(const float4*)(Af + (size_t)r*TBINS + c4);
  }
  __syncthreads();
  gj_invert64(P, colk, rowk, tid);
  for (int v = tid; v < 1024; v += 256){
    int r = v >> 4, c4 = (v & 15) << 2;
    *(float4*)(Pout + f*4096 + r*64 + c4) = *(float4*)&P[r*PAD + c4];
  }
}

// ---------------- GJ apply step: src -> dst; pivot inverse from Pin; designated
// block (k+1,k+1) also inverts its output tile -> Pout ----------------
#define ACC4(tm, fm) \
  tm[0] += fm.x*s0.x + fm.y*s1.x + fm.z*s2.x + fm.w*s3.x; \
  tm[1] += fm.x*s0.y + fm.y*s1.y + fm.z*s2.y + fm.w*s3.y; \
  tm[2] += fm.x*s0.z + fm.y*s1.z + fm.z*s2.z + fm.w*s3.z; \
  tm[3] += fm.x*s0.w + fm.y*s1.w + fm.z*s2.w + fm.w*s3.w;

__global__ __launch_bounds__(256) void gj_apply(const float* __restrict__ src,
                                                float* __restrict__ dst,
                                                const float* __restrict__ Pin,
                                                float* __restrict__ Pout,
                                                int k, int inv_next){
  __shared__ float P[64*PAD];
  __shared__ float Q[64*PAD];
  __shared__ float F[64*PAD];
  __shared__ float colk[64];
  __shared__ float rowk[64];
  int f  = blockIdx.y;
  int ti = blockIdx.x >> 3, tj = blockIdx.x & 7;
  int tid = threadIdx.x;
  const float* A = src + (size_t)f*TBINS*TBINS;
  float* D = dst + (size_t)f*TBINS*TBINS;

  // load pivot inverse (precomputed)
  for (int v = tid; v < 1024; v += 256){
    int r = v >> 4, c4 = (v & 15) << 2;
    *(float4*)&P[r*PAD + c4] = *(const float4*)(Pin + f*4096 + r*64 + c4);
  }
  if (tj != k){
    for (int v = tid; v < 1024; v += 256){
      int r = v >> 4, c4 = (v & 15) << 2;
      *(float4*)&Q[r*PAD + c4] = *(const float4*)(A + (size_t)(k*64+r)*TBINS + tj*64 + c4);
    }
  }
  if (ti != k){
    for (int v = tid; v < 1024; v += 256){
      int r = v >> 4, c4 = (v & 15) << 2;
      *(float4*)&F[r*PAD + c4] = *(const float4*)(A + (size_t)(ti*64+r)*TBINS + k*64 + c4);
    }
  }
  __syncthreads();

  int jg = (tid & 15) << 2;   // output cols jg..jg+3
  int ib = (tid >> 4) << 2;   // output rows ib..ib+3

  if (tj == k){
    if (ti == k){
      // pass-through: D[k][k] = P
      for (int v = tid; v < 1024; v += 256){
        int r = v >> 4, c4 = (v & 15) << 2;
        *(float4*)(D + (size_t)(k*64+r)*TBINS + k*64 + c4) = *(float4*)&P[r*PAD + c4];
      }
      return;
    }
    // D = -F @ P
    float w[4][4] = {{0.f,0.f,0.f,0.f},{0.f,0.f,0.f,0.f},{0.f,0.f,0.f,0.f},{0.f,0.f,0.f,0.f}};
    for (int u4 = 0; u4 < 64; u4 += 4){
      float4 f0 = *(float4*)&F[(ib+0)*PAD + u4];
      float4 f1 = *(float4*)&F[(ib+1)*PAD + u4];
      float4 f2 = *(float4*)&F[(ib+2)*PAD + u4];
      float4 f3 = *(float4*)&F[(ib+3)*PAD + u4];
      float4 s0 = *(float4*)&P[(u4+0)*PAD + jg];
      float4 s1 = *(float4*)&P[(u4+1)*PAD + jg];
      float4 s2 = *(float4*)&P[(u4+2)*PAD + jg];
      float4 s3 = *(float4*)&P[(u4+3)*PAD + jg];
      ACC4(w[0], f0); ACC4(w[1], f1); ACC4(w[2], f2); ACC4(w[3], f3);
    }
    #pragma unroll
    for (int m = 0; m < 4; ++m)
      *(float4*)(D + (size_t)(ti*64+ib+m)*TBINS + k*64 + jg)
        = make_float4(-w[m][0], -w[m][1], -w[m][2], -w[m][3]);
    return;
  }

  // tj != k: T = P @ Q (P symmetric: P'[ib][u] = P[u][ib])
  float t[4][4] = {{0.f,0.f,0.f,0.f},{0.f,0.f,0.f,0.f},{0.f,0.f,0.f,0.f},{0.f,0.f,0.f,0.f}};
  for (int u = 0; u < 64; ++u){
    float4 pv = *(float4*)&P[u*PAD + ib];
    float4 qv = *(float4*)&Q[u*PAD + jg];
    t[0][0]+=pv.x*qv.x; t[0][1]+=pv.x*qv.y; t[0][2]+=pv.x*qv.z; t[0][3]+=pv.x*qv.w;
    t[1][0]+=pv.y*qv.x; t[1][1]+=pv.y*qv.y; t[1][2]+=pv.y*qv.z; t[1][3]+=pv.y*qv.w;
    t[2][0]+=pv.z*qv.x; t[2][1]+=pv.z*qv.y; t[2][2]+=pv.z*qv.z; t[2][3]+=pv.z*qv.w;
    t[3][0]+=pv.w*qv.x; t[3][1]+=pv.w*qv.y; t[3][2]+=pv.w*qv.z; t[3][3]+=pv.w*qv.w;
  }
  if (ti == k){
    // D = T directly from registers
    #pragma unroll
    for (int m = 0; m < 4; ++m)
      *(float4*)(D + (size_t)(k*64+ib+m)*TBINS + tj*64 + jg)
        = make_float4(t[m][0],t[m][1],t[m][2],t[m][3]);
    return;
  }
  __syncthreads();               // all reads of Q done
  #pragma unroll
  for (int m = 0; m < 4; ++m)
    *(float4*)&Q[(ib+m)*PAD + jg] = make_float4(t[m][0],t[m][1],t[m][2],t[m][3]);
  __syncthreads();               // T visible to all

  // Schur: D = A[ti][tj] - F @ T
  float w[4][4] = {{0.f,0.f,0.f,0.f},{0.f,0.f,0.f,0.f},{0.f,0.f,0.f,0.f},{0.f,0.f,0.f,0.f}};
  for (int u4 = 0; u4 < 64; u4 += 4){
    float4 f0 = *(float4*)&F[(ib+0)*PAD + u4];
    float4 f1 = *(float4*)&F[(ib+1)*PAD + u4];
    float4 f2 = *(float4*)&F[(ib+2)*PAD + u4];
    float4 f3 = *(float4*)&F[(ib+3)*PAD + u4];
    float4 s0 = *(float4*)&Q[(u4+0)*PAD + jg];
    float4 s1 = *(float4*)&Q[(u4+1)*PAD + jg];
    float4 s2 = *(float4*)&Q[(u4+2)*PAD + jg];
    float4 s3 = *(float4*)&Q[(u4+3)*PAD + jg];
    ACC4(w[0], f0); ACC4(w[1], f1); ACC4(w[2], f2); ACC4(w[3], f3);
  }
  #pragma unroll
  for (int m = 0; m < 4; ++m){
    float4 av = *(const float4*)(A + (size_t)(ti*64+ib+m)*TBINS + tj*64 + jg);
    float4 dv = make_float4(av.x - w[m][0], av.y - w[m][1], av.z - w[m][2], av.w - w[m][3]);
    *(float4*)(D + (size_t)(ti*64+ib+m)*TBINS + tj*64 + jg) = dv;
    w[m][0] = dv.x; w[m][1] = dv.y; w[m][2] = dv.z; w[m][3] = dv.w;
  }

  // designated block also inverts its tile -> next step's pivot inverse
  if (inv_next && ti == k+1 && tj == k+1){
    __syncthreads();
    #pragma unroll
    for (int m = 0; m < 4; ++m)
      *(float4*)&P[(ib+m)*PAD + jg] = make_float4(w[m][0],w[m][1],w[m][2],w[m][3]);
    __syncthreads();
    gj_invert64(P, colk, rowk, tid);
    for (int v = tid; v < 1024; v += 256){
      int r = v >> 4, c4 = (v & 15) << 2;
      *(float4*)(Pout + f*4096 + r*64 + c4) = *(float4*)&P[r*PAD + c4];
    }
  }
}

// ---------------- term1: bt[(t*8+i)*128+c] = sum_n crvV[i][n] spike[c][n][t] - cdV[i] ----------------
__global__ void term1_kernel(const float* __restrict__ spike, const float* __restrict__ crvVT,
                             const float* __restrict__ cdV, float* __restrict__ bt){
  __shared__ float crl[NNEU*NF];   // [n][i]
  __shared__ float ot[128][17];
  int t0 = blockIdx.x * 16;
  int c0 = blockIdx.y * 16;
  int tid = threadIdx.x;           // 256
  int tl = tid & 15, cl = tid >> 4;
  for (int n2 = tid; n2 < NNEU*NF; n2 += 256) crl[n2] = crvVT[n2];
  __syncthreads();
  float acc[8] = {0.f,0.f,0.f,0.f,0.f,0.f,0.f,0.f};
  const float* Sp = spike + (size_t)(c0+cl)*NNEU*TBINS + t0 + tl;
  for (int n = 0; n < NNEU; n += 4){
    float s0 = Sp[(size_t)(n+0)*TBINS];
    float s1 = Sp[(size_t)(n+1)*TBINS];
    float s2 = Sp[(size_t)(n+2)*TBINS];
    float s3 = Sp[(size_t)(n+3)*TBINS];
    #pragma unroll
    for (int i = 0; i < 8; ++i)
      acc[i] += crl[(n+0)*8+i]*s0 + crl[(n+1)*8+i]*s1 + crl[(n+2)*8+i]*s2 + crl[(n+3)*8+i]*s3;
  }
  #pragma unroll
  for (int i = 0; i < 8; ++i) ot[tl*8+i][cl] = acc[i] - cdV[i];
  __syncthreads();
  int row = tid >> 1, off = (tid & 1) * 8;    // row = tlocal*8+i
  int tt = t0 + (row >> 3), ii = row & 7;
  float* dst = bt + (size_t)(tt*8+ii)*NTRI + c0 + off;
  #pragma unroll
  for (int k = 0; k < 8; ++k) dst[k] = ot[row][off+k];
}

// ---------------- batched GEMM: xt_i = H_i (512x512) @ bt_i (512x128) ----------------
__global__ void gemm_kernel(const float* __restrict__ H, const float* __restrict__ bt,
                            float* __restrict__ xt){
  __shared__ float Ht[32][68];
  __shared__ float Bt[64][128];
  int i  = blockIdx.y;
  int t0 = blockIdx.x * 32;
  int tid = threadIdx.x;           // 256
  int gt = tid >> 5;               // 0..7
  int gc = tid & 31;               // 0..31
  float acc[4][4] = {{0.f,0.f,0.f,0.f},{0.f,0.f,0.f,0.f},{0.f,0.f,0.f,0.f},{0.f,0.f,0.f,0.f}};
  const float* Hi = H + (size_t)i*TBINS*TBINS;
  for (int uc = 0; uc < 8; ++uc){
    int u0 = uc*64;
    __syncthreads();
    for (int v = tid; v < 512; v += 256){
      int r = v >> 4, c4 = (v & 15) << 2;
      *(float4*)&Ht[r][c4] = *(const float4*)(Hi + (size_t)(t0+r)*TBINS + u0 + c4);
    }
    for (int v = tid; v < 2048; v += 256){
      int r = v >> 5, c4 = (v & 31) << 2;
      *(float4*)&Bt[r][c4] = *(const float4*)(bt + (size_t)((u0+r)*8 + i)*NTRI + c4);
    }
    __syncthreads();
    for (int u = 0; u < 64; ++u){
      float h0 = Ht[gt*4+0][u], h1 = Ht[gt*4+1][u], h2 = Ht[gt*4+2][u], h3 = Ht[gt*4+3][u];
      float b0 = Bt[u][gc], b1 = Bt[u][gc+32], b2 = Bt[u][gc+64], b3 = Bt[u][gc+96];
      acc[0][0] += h0*b0; acc[0][1] += h0*b1; acc[0][2] += h0*b2; acc[0][3] += h0*b3;
      acc[1][0] += h1*b0; acc[1][1] += h1*b1; acc[1][2] += h1*b2; acc[1][3] += h1*b3;
      acc[2][0] += h2*b0; acc[2][1] += h2*b1; acc[2][2] += h2*b2; acc[2][3] += h2*b3;
      acc[3][0] += h3*b0; acc[3][1] += h3*b1; acc[3][2] += h3*b2; acc[3][3] += h3*b3;
    }
  }
  #pragma unroll
  for (int m = 0; m < 4; ++m)
    #pragma unroll
    for (int j = 0; j < 4; ++j)
      xt[(size_t)((t0 + gt*4 + m)*8 + i)*NTRI + gc + 32*j] = acc[m][j];
}

// ---------------- output: out[c][f][t] = sum_i V[f][i] xt[(t*8+i)*128+c] ----------------
__global__ void output_kernel(const float* __restrict__ xt, const float* __restrict__ Vf,
                              float* __restrict__ out){
  __shared__ float T[128][68];
  __shared__ float Vl[64];
  int t0 = blockIdx.x * 64, c0 = blockIdx.y * 16;
  int tid = threadIdx.x;   // 256
  if (tid < 64) Vl[tid] = Vf[tid];
  __syncthreads();
  for (int idx = tid; idx < 1024; idx += 256){
    int tl = idx >> 4, cl = idx & 15;
    float xv[8];
    #pragma unroll
    for (int i = 0; i < 8; ++i)
      xv[i] = xt[(size_t)((t0+tl)*8+i)*NTRI + c0 + cl];
    #pragma unroll
    for (int f = 0; f < 8; ++f){
      float s = 0.f;
      #pragma unroll
      for (int i = 0; i < 8; ++i) s += Vl[f*8+i] * xv[i];
      T[cl*8+f][tl] = s;
    }
  }
  __syncthreads();
  int row = tid >> 1, half = tid & 1;   // row = cl*8+f
  int cc = c0 + (row >> 3), ff = row & 7;
  float* dst = out + (size_t)cc*NF*TBINS + ff*TBINS + t0 + half*32;
  #pragma unroll
  for (int k = 0; k < 8; ++k)
    ((float4*)dst)[k] = *(float4*)&T[row][half*32 + k*4];
}

extern "C" void kernel_launch(void* const* d_in, const int* in_sizes, int n_in,
                              void* d_out, int out_size, void* d_ws, size_t ws_size,
                              hipStream_t stream) {
  const float* spike  = (const float*)d_in[0];
  const float* Cm     = (const float*)d_in[1];
  const float* dm     = (const float*)d_in[2];
  const float* r_diag = (const float*)d_in[3];
  const float* gamma  = (const float*)d_in[4];
  float* out = (float*)d_out;
  float* ws = (float*)d_ws;

  float*  A0    = ws + OFF_A0;
  float*  A1    = ws + OFF_A1;
  float*  crvT  = ws + OFF_CRVT;
  float*  crvVT = ws + OFF_CRVVT;
  float*  ccT   = ws + OFF_CCT;
  float*  cd    = ws + OFF_CD;
  float*  cdV   = ws + OFF_CDV;
  float*  rinv  = ws + OFF_RINV;
  float*  lam   = ws + OFF_LAM;
  float*  Vf    = ws + OFF_VF;
  float*  bt    = ws + OFF_BT;
  float*  xt    = ws + OFF_XT;
  float*  Pb[2] = { ws + OFF_PP0, ws + OFF_PP1 };

  prep_kernel<<<1, 512, 0, stream>>>(Cm, dm, r_diag, crvT, ccT, cd, rinv);
  eig8_kernel<<<1, 64, 0, stream>>>(ccT, Vf, lam);
  rotv_kernel<<<1, 512, 0, stream>>>(crvT, cd, Vf, crvVT, cdV);
  buildK_kernel<<<dim3(1024, 8), 256, 0, stream>>>(gamma, A0);

  // chain 1: invert K_f (ping-pong A0 <-> A1, 8 steps -> result in A0)
  gj_pivot0<<<8, 256, 0, stream>>>(A0, Pb[0]);
  {
    float* s = A0; float* d = A1;
    for (int k = 0; k < 8; ++k){
      gj_apply<<<dim3(64, 8), 256, 0, stream>>>(s, d, Pb[k&1], Pb[(k+1)&1], k, (k < 7) ? 1 : 0);
      float* tmp = s; s = d; d = tmp;
    }
  }
  buildG_kernel<<<1024, 256, 0, stream>>>(A0, lam, A1);
  // chain 2: invert G_i (start A1, 8 steps -> H in A1)
  gj_pivot0<<<8, 256, 0, stream>>>(A1, Pb[0]);
  {
    float* s = A1; float* d = A0;
    for (int k = 0; k < 8; ++k){
      gj_apply<<<dim3(64, 8), 256, 0, stream>>>(s, d, Pb[k&1], Pb[(k+1)&1], k, (k < 7) ? 1 : 0);
      float* tmp = s; s = d; d = tmp;
    }
  }
  term1_kernel<<<dim3(32, 8), 256, 0, stream>>>(spike, crvVT, cdV, bt);
  gemm_kernel<<<dim3(16, 8), 256, 0, stream>>>(A1, bt, xt);
  output_kernel<<<dim3(8, 8), 256, 0, stream>>>(xt, Vf, out);
}

// Round 3
// 1271.990 us; speedup vs baseline: 2.0294x; 1.9768x over previous
//
#include <hip/hip_runtime.h>

// GPFA e-step posterior mean on MI355X — direct Kronecker-sum solve, fp32 chains.
// M = Kbar (x) I_F + I_T (x) A,  Kbar = sum_f inv(K_f),  A = C'R^-1 C = V Lam V'.
// Per factor-eigenpair i: (Kbar + lam_i I) xt_i = bt_i  (512x512, 128 RHS).
// GJ chains: one apply-kernel per step (pure tile GEMMs, pivot inverse read from
// global); the NEXT step's 64x64 pivot inversion is fused into the single
// designated block that produces tile (k+1,k+1).
//
// R2: eig8 wave-parallel via shfl (was 155 us of scratch latency).
// R3: pivot inversion rewritten as single-wave REGISTER GJ (lane j owns column j,
// 64 VGPRs; readlane broadcasts; template-forced full unroll -> no scratch, no
// barriers, no LDS). Was: 64 iters x 2 syncthreads x LDS round-trips ~120 us of
// one-block serial tail per gj_apply dispatch (occupancy 2% proved it). Same
// expression tree as the old LDS version -> numerics preserved.

#define NF 8
#define TBINS 512
#define NNEU 512
#define NTRI 128
#define PAD 68

// ---- ws layout (float offsets) ----
#define OFF_A0     0                 // float[8*512*512] ping
#define OFF_A1     2097152           // float[8*512*512] pong
#define OFF_CRVT   4194304           // float[512*8]
#define OFF_CRVVT  4198400           // float[512*8]
#define OFF_CCT    4202496           // float[64]
#define OFF_CD     4202560           // float[64]
#define OFF_CDV    4202624           // float[64]
#define OFF_RINV   4202688           // float[512]
#define OFF_LAM    4203200           // float[8]
#define OFF_VF     4203216           // float[64]
#define OFF_BT     4203280           // float[4096*128]
#define OFF_XT     4727568           // float[4096*128]
#define OFF_PP0    5251856           // float[8*4096] pivot-inverse buf A
#define OFF_PP1    5284624           // float[8*4096] pivot-inverse buf B

__device__ __forceinline__ void load8(float* v, const float* ptr){
  float4 a = ((const float4*)ptr)[0];
  float4 b = ((const float4*)ptr)[1];
  v[0]=a.x; v[1]=a.y; v[2]=a.z; v[3]=a.w;
  v[4]=b.x; v[5]=b.y; v[6]=b.z; v[7]=b.w;
}
__device__ __forceinline__ void store8(float* ptr, const float* v){
  ((float4*)ptr)[0] = make_float4(v[0],v[1],v[2],v[3]);
  ((float4*)ptr)[1] = make_float4(v[4],v[5],v[6],v[7]);
}

// ---------------- single-wave register GJ inversion of 64x64 SPD tile ----------------
// Lane j owns column j: c[i] = P[i][j]. Template KK forces compile-time indices
// (SROA keeps c[] in VGPRs). readlane broadcasts lane KK's values (uniform->SGPR).
// Expression-identical to the former LDS gj_invert64:
//   P[kk][kk]=pinv; P[i][kk]=-colk[i]*pinv; P[kk][j]=rowk[j]*pinv;
//   P[i][j]-=colk[i]*(rowk[j]*pinv).
__device__ __forceinline__ float rlane(float v, int l){
  return __int_as_float(__builtin_amdgcn_readlane(__float_as_int(v), l));
}

template<int KK>
__device__ __forceinline__ void gj_reg_step(float (&c)[64], int lane){
  float pivot = rlane(c[KK], KK);
  float pinv  = 1.0f / pivot;
  float newr  = c[KK] * pinv;        // new P[KK][j] for my column
  bool iskk = (lane == KK);
  #pragma unroll
  for (int i = 0; i < KK; ++i){
    float pc = rlane(c[i], KK);      // P[i][KK] (uniform)
    c[i] = iskk ? (-pc * pinv) : (c[i] - pc * newr);
  }
  #pragma unroll
  for (int i = KK + 1; i < 64; ++i){
    float pc = rlane(c[i], KK);
    c[i] = iskk ? (-pc * pinv) : (c[i] - pc * newr);
  }
  c[KK] = iskk ? pinv : newr;
}

template<int KK> struct GJChain {
  static __device__ __forceinline__ void run(float (&c)[64], int lane){
    gj_reg_step<KK>(c, lane);
    GJChain<KK + 1>::run(c, lane);
  }
};
template<> struct GJChain<64> {
  static __device__ __forceinline__ void run(float (&c)[64], int lane){}
};

// ---------------- prep ----------------
__global__ void prep_kernel(const float* __restrict__ Cm, const float* __restrict__ dm,
                            const float* __restrict__ r_diag,
                            float* __restrict__ crvT, float* __restrict__ ccT,
                            float* __restrict__ cd, float* __restrict__ rinv){
  __shared__ float s_crv[NNEU*NF];
  __shared__ float s_cm[NNEU*NF];
  __shared__ float s_dm[NNEU];
  int tid = threadIdx.x;            // 512; thread == neuron n
  float ri = 1.0f / r_diag[tid];
  rinv[tid] = ri;
  s_dm[tid] = dm[tid];
  #pragma unroll
  for (int f = 0; f < NF; ++f){
    float cv = Cm[tid*NF + f];
    s_cm[tid*NF + f] = cv;
    float v = cv * ri;
    s_crv[tid*NF + f] = v;
    crvT[tid*NF + f] = v;
  }
  __syncthreads();
  if (tid < 64){
    int f = tid >> 3, g = tid & 7;
    float acc = 0.f;
    for (int n = 0; n < NNEU; ++n) acc += s_crv[n*NF+f] * s_cm[n*NF+g];
    ccT[tid] = acc;
  } else if (tid < 72){
    int f = tid - 64;
    float acc = 0.f;
    for (int n = 0; n < NNEU; ++n) acc += s_crv[n*NF+f] * s_dm[n];
    cd[f] = acc;
  }
}

// ---------------- 8x8 eig: cyclic Jacobi, wave-parallel, fp32 ----------------
__global__ void eig8_kernel(const float* __restrict__ ccT,
                            float* __restrict__ Vf, float* __restrict__ lam){
  int lane = threadIdx.x & 63;      // one wave, 64 lanes
  int a = lane >> 3, b = lane & 7;
  float Av = ccT[lane];
  float Vv = (a == b) ? 1.0f : 0.0f;
  for (int sw = 0; sw < 8; ++sw){
    for (int p = 0; p < 7; ++p){
      for (int q = p + 1; q < 8; ++q){
        float apq = __shfl(Av, p*8 + q, 64);
        if (fabsf(apq) < 1e-20f) continue;          // uniform: apq is wave-broadcast
        float app = __shfl(Av, p*8 + p, 64);
        float aqq = __shfl(Av, q*8 + q, 64);
        float beta = (aqq - app) / (2.0f * apq);
        float tt = ((beta >= 0.0f) ? 1.0f : -1.0f) / (fabsf(beta) + sqrtf(1.0f + beta*beta));
        float c = 1.0f / sqrtf(1.0f + tt*tt);
        float s = tt * c;
        int bp = (b == p) ? q : (b == q) ? p : b;   // partner column
        float Ac = __shfl(Av, a*8 + bp, 64);        // snapshot before writes
        float Vc = __shfl(Vv, a*8 + bp, 64);
        if (b == p)      { Av = c*Av - s*Ac;  Vv = c*Vv - s*Vc; }
        else if (b == q) { Av = s*Ac + c*Av;  Vv = s*Vc + c*Vv; }
        int ap = (a == p) ? q : (a == q) ? p : a;   // partner row
        float Ar = __shfl(Av, ap*8 + b, 64);
        if (a == p)      Av = c*Av - s*Ar;
        else if (a == q) Av = s*Ar + c*Av;
      }
    }
  }
  if (a == b) lam[a] = Av;
  Vf[lane] = Vv;
}

// ---------------- rotate crv, cd by V^T ----------------
__global__ void rotv_kernel(const float* __restrict__ crvT, const float* __restrict__ cd,
                            const float* __restrict__ Vf,
                            float* __restrict__ crvVT, float* __restrict__ cdV){
  __shared__ float Vl[64];
  int tid = threadIdx.x;   // 512
  if (tid < 64) Vl[tid] = Vf[tid];
  __syncthreads();
  float cv[8], ov[8];
  load8(cv, crvT + tid*8);
  #pragma unroll
  for (int i = 0; i < 8; ++i){
    float s = 0.f;
    #pragma unroll
    for (int f = 0; f < 8; ++f) s += Vl[f*8+i] * cv[f];
    ov[i] = s;
  }
  store8(crvVT + tid*8, ov);
  if (tid < 8){
    float s = 0.f;
    #pragma unroll
    for (int f = 0; f < 8; ++f) s += Vl[f*8+tid] * cd[f];
    cdV[tid] = s;
  }
}

// ---------------- build K_f (fp32) ----------------
__global__ void buildK_kernel(const float* __restrict__ gamma, float* __restrict__ A0){
  int f = blockIdx.y;
  int idx = blockIdx.x*256 + threadIdx.x;   // t*512+u
  int t = idx >> 9, u = idx & 511;
  float g = gamma[f];
  float d = (float)(t - u);
  float v = 0.999f * expf(-0.5f * g * d * d);
  if (t == u) v += 1.0e-3f;
  A0[(size_t)f*TBINS*TBINS + idx] = v;
}

// ---------------- G_i = (sum_f Kinv_f) + lam_i I ----------------
__global__ void buildG_kernel(const float* __restrict__ A0, const float* __restrict__ lam,
                              float* __restrict__ A1){
  int idx = blockIdx.x*256 + threadIdx.x;       // 0..262143
  float s = 0.f;
  #pragma unroll
  for (int f2 = 0; f2 < NF; ++f2) s += A0[(size_t)f2*TBINS*TBINS + idx];
  bool diag = ((idx >> 9) == (idx & 511));
  #pragma unroll
  for (int i = 0; i < NF; ++i)
    A1[(size_t)i*TBINS*TBINS + idx] = s + (diag ? lam[i] : 0.f);
}

// ---------------- standalone pivot inversion (chain head): Pout = inv(A[f][0:64][0:64]) ----------------
// One wave per factor; lane j owns column j in registers.
__global__ __launch_bounds__(64) void gj_pivot0(const float* __restrict__ A,
                                                float* __restrict__ Pout){
  int f = blockIdx.x;
  int lane = threadIdx.x;           // 64
  const float* Af = A + (size_t)f*TBINS*TBINS;
  float c[64];
  #pragma unroll
  for (int i = 0; i < 64; ++i) c[i] = Af[(size_t)i*TBINS + lane];   // coalesced per i
  GJChain<0>::run(c, lane);
  #pragma unroll
  for (int i = 0; i < 64; ++i) Pout[f*4096 + i*64 + lane] = c[i];   // coalesced per i
}

// ---------------- GJ apply step: src -> dst; pivot inverse from Pin; designated
// block (k+1,k+1) also inverts its output tile -> Pout ----------------
#define ACC4(tm, fm) \
  tm[0] += fm.x*s0.x + fm.y*s1.x + fm.z*s2.x + fm.w*s3.x; \
  tm[1] += fm.x*s0.y + fm.y*s1.y + fm.z*s2.y + fm.w*s3.y; \
  tm[2] += fm.x*s0.z + fm.y*s1.z + fm.z*s2.z + fm.w*s3.z; \
  tm[3] += fm.x*s0.w + fm.y*s1.w + fm.z*s2.w + fm.w*s3.w;

__global__ __launch_bounds__(256) void gj_apply(const float* __restrict__ src,
                                                float* __restrict__ dst,
                                                const float* __restrict__ Pin,
                                                float* __restrict__ Pout,
                                                int k, int inv_next){
  __shared__ float P[64*PAD];
  __shared__ float Q[64*PAD];
  __shared__ float F[64*PAD];
  int f  = blockIdx.y;
  int ti = blockIdx.x >> 3, tj = blockIdx.x & 7;
  int tid = threadIdx.x;
  const float* A = src + (size_t)f*TBINS*TBINS;
  float* D = dst + (size_t)f*TBINS*TBINS;

  // load pivot inverse (precomputed)
  for (int v = tid; v < 1024; v += 256){
    int r = v >> 4, c4 = (v & 15) << 2;
    *(float4*)&P[r*PAD + c4] = *(const float4*)(Pin + f*4096 + r*64 + c4);
  }
  if (tj != k){
    for (int v = tid; v < 1024; v += 256){
      int r = v >> 4, c4 = (v & 15) << 2;
      *(float4*)&Q[r*PAD + c4] = *(const float4*)(A + (size_t)(k*64+r)*TBINS + tj*64 + c4);
    }
  }
  if (ti != k){
    for (int v = tid; v < 1024; v += 256){
      int r = v >> 4, c4 = (v & 15) << 2;
      *(float4*)&F[r*PAD + c4] = *(const float4*)(A + (size_t)(ti*64+r)*TBINS + k*64 + c4);
    }
  }
  __syncthreads();

  int jg = (tid & 15) << 2;   // output cols jg..jg+3
  int ib = (tid >> 4) << 2;   // output rows ib..ib+3

  if (tj == k){
    if (ti == k){
      // pass-through: D[k][k] = P
      for (int v = tid; v < 1024; v += 256){
        int r = v >> 4, c4 = (v & 15) << 2;
        *(float4*)(D + (size_t)(k*64+r)*TBINS + k*64 + c4) = *(float4*)&P[r*PAD + c4];
      }
      return;
    }
    // D = -F @ P
    float w[4][4] = {{0.f,0.f,0.f,0.f},{0.f,0.f,0.f,0.f},{0.f,0.f,0.f,0.f},{0.f,0.f,0.f,0.f}};
    for (int u4 = 0; u4 < 64; u4 += 4){
      float4 f0 = *(float4*)&F[(ib+0)*PAD + u4];
      float4 f1 = *(float4*)&F[(ib+1)*PAD + u4];
      float4 f2 = *(float4*)&F[(ib+2)*PAD + u4];
      float4 f3 = *(float4*)&F[(ib+3)*PAD + u4];
      float4 s0 = *(float4*)&P[(u4+0)*PAD + jg];
      float4 s1 = *(float4*)&P[(u4+1)*PAD + jg];
      float4 s2 = *(float4*)&P[(u4+2)*PAD + jg];
      float4 s3 = *(float4*)&P[(u4+3)*PAD + jg];
      ACC4(w[0], f0); ACC4(w[1], f1); ACC4(w[2], f2); ACC4(w[3], f3);
    }
    #pragma unroll
    for (int m = 0; m < 4; ++m)
      *(float4*)(D + (size_t)(ti*64+ib+m)*TBINS + k*64 + jg)
        = make_float4(-w[m][0], -w[m][1], -w[m][2], -w[m][3]);
    return;
  }

  // tj != k: T = P @ Q (P symmetric: P'[ib][u] = P[u][ib])
  float t[4][4] = {{0.f,0.f,0.f,0.f},{0.f,0.f,0.f,0.f},{0.f,0.f,0.f,0.f},{0.f,0.f,0.f,0.f}};
  for (int u = 0; u < 64; ++u){
    float4 pv = *(float4*)&P[u*PAD + ib];
    float4 qv = *(float4*)&Q[u*PAD + jg];
    t[0][0]+=pv.x*qv.x; t[0][1]+=pv.x*qv.y; t[0][2]+=pv.x*qv.z; t[0][3]+=pv.x*qv.w;
    t[1][0]+=pv.y*qv.x; t[1][1]+=pv.y*qv.y; t[1][2]+=pv.y*qv.z; t[1][3]+=pv.y*qv.w;
    t[2][0]+=pv.z*qv.x; t[2][1]+=pv.z*qv.y; t[2][2]+=pv.z*qv.z; t[2][3]+=pv.z*qv.w;
    t[3][0]+=pv.w*qv.x; t[3][1]+=pv.w*qv.y; t[3][2]+=pv.w*qv.z; t[3][3]+=pv.w*qv.w;
  }
  if (ti == k){
    // D = T directly from registers
    #pragma unroll
    for (int m = 0; m < 4; ++m)
      *(float4*)(D + (size_t)(k*64+ib+m)*TBINS + tj*64 + jg)
        = make_float4(t[m][0],t[m][1],t[m][2],t[m][3]);
    return;
  }
  __syncthreads();               // all reads of Q done
  #pragma unroll
  for (int m = 0; m < 4; ++m)
    *(float4*)&Q[(ib+m)*PAD + jg] = make_float4(t[m][0],t[m][1],t[m][2],t[m][3]);
  __syncthreads();               // T visible to all

  // Schur: D = A[ti][tj] - F @ T
  float w[4][4] = {{0.f,0.f,0.f,0.f},{0.f,0.f,0.f,0.f},{0.f,0.f,0.f,0.f},{0.f,0.f,0.f,0.f}};
  for (int u4 = 0; u4 < 64; u4 += 4){
    float4 f0 = *(float4*)&F[(ib+0)*PAD + u4];
    float4 f1 = *(float4*)&F[(ib+1)*PAD + u4];
    float4 f2 = *(float4*)&F[(ib+2)*PAD + u4];
    float4 f3 = *(float4*)&F[(ib+3)*PAD + u4];
    float4 s0 = *(float4*)&Q[(u4+0)*PAD + jg];
    float4 s1 = *(float4*)&Q[(u4+1)*PAD + jg];
    float4 s2 = *(float4*)&Q[(u4+2)*PAD + jg];
    float4 s3 = *(float4*)&Q[(u4+3)*PAD + jg];
    ACC4(w[0], f0); ACC4(w[1], f1); ACC4(w[2], f2); ACC4(w[3], f3);
  }
  #pragma unroll
  for (int m = 0; m < 4; ++m){
    float4 av = *(const float4*)(A + (size_t)(ti*64+ib+m)*TBINS + tj*64 + jg);
    float4 dv = make_float4(av.x - w[m][0], av.y - w[m][1], av.z - w[m][2], av.w - w[m][3]);
    *(float4*)(D + (size_t)(ti*64+ib+m)*TBINS + tj*64 + jg) = dv;
    w[m][0] = dv.x; w[m][1] = dv.y; w[m][2] = dv.z; w[m][3] = dv.w;
  }

  // designated block: next step's pivot inverse via single-wave register GJ
  if (inv_next && ti == k+1 && tj == k+1){
    __syncthreads();
    #pragma unroll
    for (int m = 0; m < 4; ++m)
      *(float4*)&P[(ib+m)*PAD + jg] = make_float4(w[m][0],w[m][1],w[m][2],w[m][3]);
    __syncthreads();
    if (tid < 64){
      float c[64];
      #pragma unroll
      for (int i = 0; i < 64; ++i) c[i] = P[i*PAD + tid];   // lane=column
      GJChain<0>::run(c, tid);
      #pragma unroll
      for (int i = 0; i < 64; ++i) Pout[f*4096 + i*64 + tid] = c[i];
    }
  }
}

// ---------------- term1: bt[(t*8+i)*128+c] = sum_n crvV[i][n] spike[c][n][t] - cdV[i] ----------------
__global__ void term1_kernel(const float* __restrict__ spike, const float* __restrict__ crvVT,
                             const float* __restrict__ cdV, float* __restrict__ bt){
  __shared__ float crl[NNEU*NF];   // [n][i]
  __shared__ float ot[128][17];
  int t0 = blockIdx.x * 16;
  int c0 = blockIdx.y * 16;
  int tid = threadIdx.x;           // 256
  int tl = tid & 15, cl = tid >> 4;
  for (int n2 = tid; n2 < NNEU*NF; n2 += 256) crl[n2] = crvVT[n2];
  __syncthreads();
  float acc[8] = {0.f,0.f,0.f,0.f,0.f,0.f,0.f,0.f};
  const float* Sp = spike + (size_t)(c0+cl)*NNEU*TBINS + t0 + tl;
  for (int n = 0; n < NNEU; n += 4){
    float s0 = Sp[(size_t)(n+0)*TBINS];
    float s1 = Sp[(size_t)(n+1)*TBINS];
    float s2 = Sp[(size_t)(n+2)*TBINS];
    float s3 = Sp[(size_t)(n+3)*TBINS];
    #pragma unroll
    for (int i = 0; i < 8; ++i)
      acc[i] += crl[(n+0)*8+i]*s0 + crl[(n+1)*8+i]*s1 + crl[(n+2)*8+i]*s2 + crl[(n+3)*8+i]*s3;
  }
  #pragma unroll
  for (int i = 0; i < 8; ++i) ot[tl*8+i][cl] = acc[i] - cdV[i];
  __syncthreads();
  int row = tid >> 1, off = (tid & 1) * 8;    // row = tlocal*8+i
  int tt = t0 + (row >> 3), ii = row & 7;
  float* dst = bt + (size_t)(tt*8+ii)*NTRI + c0 + off;
  #pragma unroll
  for (int k = 0; k < 8; ++k) dst[k] = ot[row][off+k];
}

// ---------------- batched GEMM: xt_i = H_i (512x512) @ bt_i (512x128) ----------------
__global__ void gemm_kernel(const float* __restrict__ H, const float* __restrict__ bt,
                            float* __restrict__ xt){
  __shared__ float Ht[32][68];
  __shared__ float Bt[64][128];
  int i  = blockIdx.y;
  int t0 = blockIdx.x * 32;
  int tid = threadIdx.x;           // 256
  int gt = tid >> 5;               // 0..7
  int gc = tid & 31;               // 0..31
  float acc[4][4] = {{0.f,0.f,0.f,0.f},{0.f,0.f,0.f,0.f},{0.f,0.f,0.f,0.f},{0.f,0.f,0.f,0.f}};
  const float* Hi = H + (size_t)i*TBINS*TBINS;
  for (int uc = 0; uc < 8; ++uc){
    int u0 = uc*64;
    __syncthreads();
    for (int v = tid; v < 512; v += 256){
      int r = v >> 4, c4 = (v & 15) << 2;
      *(float4*)&Ht[r][c4] = *(const float4*)(Hi + (size_t)(t0+r)*TBINS + u0 + c4);
    }
    for (int v = tid; v < 2048; v += 256){
      int r = v >> 5, c4 = (v & 31) << 2;
      *(float4*)&Bt[r][c4] = *(const float4*)(bt + (size_t)((u0+r)*8 + i)*NTRI + c4);
    }
    __syncthreads();
    for (int u = 0; u < 64; ++u){
      float h0 = Ht[gt*4+0][u], h1 = Ht[gt*4+1][u], h2 = Ht[gt*4+2][u], h3 = Ht[gt*4+3][u];
      float b0 = Bt[u][gc], b1 = Bt[u][gc+32], b2 = Bt[u][gc+64], b3 = Bt[u][gc+96];
      acc[0][0] += h0*b0; acc[0][1] += h0*b1; acc[0][2] += h0*b2; acc[0][3] += h0*b3;
      acc[1][0] += h1*b0; acc[1][1] += h1*b1; acc[1][2] += h1*b2; acc[1][3] += h1*b3;
      acc[2][0] += h2*b0; acc[2][1] += h2*b1; acc[2][2] += h2*b2; acc[2][3] += h2*b3;
      acc[3][0] += h3*b0; acc[3][1] += h3*b1; acc[3][2] += h3*b2; acc[3][3] += h3*b3;
    }
  }
  #pragma unroll
  for (int m = 0; m < 4; ++m)
    #pragma unroll
    for (int j = 0; j < 4; ++j)
      xt[(size_t)((t0 + gt*4 + m)*8 + i)*NTRI + gc + 32*j] = acc[m][j];
}

// ---------------- output: out[c][f][t] = sum_i V[f][i] xt[(t*8+i)*128+c] ----------------
__global__ void output_kernel(const float* __restrict__ xt, const float* __restrict__ Vf,
                              float* __restrict__ out){
  __shared__ float T[128][68];
  __shared__ float Vl[64];
  int t0 = blockIdx.x * 64, c0 = blockIdx.y * 16;
  int tid = threadIdx.x;   // 256
  if (tid < 64) Vl[tid] = Vf[tid];
  __syncthreads();
  for (int idx = tid; idx < 1024; idx += 256){
    int tl = idx >> 4, cl = idx & 15;
    float xv[8];
    #pragma unroll
    for (int i = 0; i < 8; ++i)
      xv[i] = xt[(size_t)((t0+tl)*8+i)*NTRI + c0 + cl];
    #pragma unroll
    for (int f = 0; f < 8; ++f){
      float s = 0.f;
      #pragma unroll
      for (int i = 0; i < 8; ++i) s += Vl[f*8+i] * xv[i];
      T[cl*8+f][tl] = s;
    }
  }
  __syncthreads();
  int row = tid >> 1, half = tid & 1;   // row = cl*8+f
  int cc = c0 + (row >> 3), ff = row & 7;
  float* dst = out + (size_t)cc*NF*TBINS + ff*TBINS + t0 + half*32;
  #pragma unroll
  for (int k = 0; k < 8; ++k)
    ((float4*)dst)[k] = *(float4*)&T[row][half*32 + k*4];
}

extern "C" void kernel_launch(void* const* d_in, const int* in_sizes, int n_in,
                              void* d_out, int out_size, void* d_ws, size_t ws_size,
                              hipStream_t stream) {
  const float* spike  = (const float*)d_in[0];
  const float* Cm     = (const float*)d_in[1];
  const float* dm     = (const float*)d_in[2];
  const float* r_diag = (const float*)d_in[3];
  const float* gamma  = (const float*)d_in[4];
  float* out = (float*)d_out;
  float* ws = (float*)d_ws;

  float*  A0    = ws + OFF_A0;
  float*  A1    = ws + OFF_A1;
  float*  crvT  = ws + OFF_CRVT;
  float*  crvVT = ws + OFF_CRVVT;
  float*  ccT   = ws + OFF_CCT;
  float*  cd    = ws + OFF_CD;
  float*  cdV   = ws + OFF_CDV;
  float*  rinv  = ws + OFF_RINV;
  float*  lam   = ws + OFF_LAM;
  float*  Vf    = ws + OFF_VF;
  float*  bt    = ws + OFF_BT;
  float*  xt    = ws + OFF_XT;
  float*  Pb[2] = { ws + OFF_PP0, ws + OFF_PP1 };

  prep_kernel<<<1, 512, 0, stream>>>(Cm, dm, r_diag, crvT, ccT, cd, rinv);
  eig8_kernel<<<1, 64, 0, stream>>>(ccT, Vf, lam);
  rotv_kernel<<<1, 512, 0, stream>>>(crvT, cd, Vf, crvVT, cdV);
  buildK_kernel<<<dim3(1024, 8), 256, 0, stream>>>(gamma, A0);

  // chain 1: invert K_f (ping-pong A0 <-> A1, 8 steps -> result in A0)
  gj_pivot0<<<8, 64, 0, stream>>>(A0, Pb[0]);
  {
    float* s = A0; float* d = A1;
    for (int k = 0; k < 8; ++k){
      gj_apply<<<dim3(64, 8), 256, 0, stream>>>(s, d, Pb[k&1], Pb[(k+1)&1], k, (k < 7) ? 1 : 0);
      float* tmp = s; s = d; d = tmp;
    }
  }
  buildG_kernel<<<1024, 256, 0, stream>>>(A0, lam, A1);
  // chain 2: invert G_i (start A1, 8 steps -> H in A1)
  gj_pivot0<<<8, 64, 0, stream>>>(A1, Pb[0]);
  {
    float* s = A1; float* d = A0;
    for (int k = 0; k < 8; ++k){
      gj_apply<<<dim3(64, 8), 256, 0, stream>>>(s, d, Pb[k&1], Pb[(k+1)&1], k, (k < 7) ? 1 : 0);
      float* tmp = s; s = d; d = tmp;
    }
  }
  term1_kernel<<<dim3(32, 8), 256, 0, stream>>>(spike, crvVT, cdV, bt);
  gemm_kernel<<<dim3(16, 8), 256, 0, stream>>>(A1, bt, xt);
  output_kernel<<<dim3(8, 8), 256, 0, stream>>>(xt, Vf, out);
}

// Round 4
// 1245.547 us; speedup vs baseline: 2.0725x; 1.0212x over previous
//
#include <hip/hip_runtime.h>

// GPFA e-step posterior mean on MI355X — direct Kronecker-sum solve, fp32 chains.
// M = Kbar (x) I_F + I_T (x) A,  Kbar = sum_f inv(K_f),  A = C'R^-1 C = V Lam V'.
// Per factor-eigenpair i: (Kbar + lam_i I) xt_i = bt_i  (512x512, 128 RHS).
// GJ chains: one apply-kernel per step (pure tile GEMMs, pivot inverse read from
// global); the NEXT step's 64x64 pivot inversion is fused into the single
// designated block that produces tile (k+1,k+1).
//
// R2: eig8 wave-parallel via shfl (was 155 us of scratch latency).
// R3: pivot inversion = single-wave register GJ (readlane broadcasts, no LDS/barriers).
// R4: term1 was latency-bound at 1.4 TB/s (256 blocks = 1/CU, occupancy 10.6%):
// split neuron-sum into 4 chunks (blockIdx.z, partials in dead A0) -> 1024 blocks,
// n-unroll 4->8 (8 loads in flight), float4 LDS weight reads; term1_reduce sums
// chunks and applies -cdV once.

#define NF 8
#define TBINS 512
#define NNEU 512
#define NTRI 128
#define PAD 68

// ---- ws layout (float offsets) ----
#define OFF_A0     0                 // float[8*512*512] ping (reused as term1 partials)
#define OFF_A1     2097152           // float[8*512*512] pong
#define OFF_CRVT   4194304           // float[512*8]
#define OFF_CRVVT  4198400           // float[512*8]
#define OFF_CCT    4202496           // float[64]
#define OFF_CD     4202560           // float[64]
#define OFF_CDV    4202624           // float[64]
#define OFF_RINV   4202688           // float[512]
#define OFF_LAM    4203200           // float[8]
#define OFF_VF     4203216           // float[64]
#define OFF_BT     4203280           // float[4096*128]
#define OFF_XT     4727568           // float[4096*128]
#define OFF_PP0    5251856           // float[8*4096] pivot-inverse buf A
#define OFF_PP1    5284624           // float[8*4096] pivot-inverse buf B

__device__ __forceinline__ void load8(float* v, const float* ptr){
  float4 a = ((const float4*)ptr)[0];
  float4 b = ((const float4*)ptr)[1];
  v[0]=a.x; v[1]=a.y; v[2]=a.z; v[3]=a.w;
  v[4]=b.x; v[5]=b.y; v[6]=b.z; v[7]=b.w;
}
__device__ __forceinline__ void store8(float* ptr, const float* v){
  ((float4*)ptr)[0] = make_float4(v[0],v[1],v[2],v[3]);
  ((float4*)ptr)[1] = make_float4(v[4],v[5],v[6],v[7]);
}

// ---------------- single-wave register GJ inversion of 64x64 SPD tile ----------------
__device__ __forceinline__ float rlane(float v, int l){
  return __int_as_float(__builtin_amdgcn_readlane(__float_as_int(v), l));
}

template<int KK>
__device__ __forceinline__ void gj_reg_step(float (&c)[64], int lane){
  float pivot = rlane(c[KK], KK);
  float pinv  = 1.0f / pivot;
  float newr  = c[KK] * pinv;        // new P[KK][j] for my column
  bool iskk = (lane == KK);
  #pragma unroll
  for (int i = 0; i < KK; ++i){
    float pc = rlane(c[i], KK);      // P[i][KK] (uniform)
    c[i] = iskk ? (-pc * pinv) : (c[i] - pc * newr);
  }
  #pragma unroll
  for (int i = KK + 1; i < 64; ++i){
    float pc = rlane(c[i], KK);
    c[i] = iskk ? (-pc * pinv) : (c[i] - pc * newr);
  }
  c[KK] = iskk ? pinv : newr;
}

template<int KK> struct GJChain {
  static __device__ __forceinline__ void run(float (&c)[64], int lane){
    gj_reg_step<KK>(c, lane);
    GJChain<KK + 1>::run(c, lane);
  }
};
template<> struct GJChain<64> {
  static __device__ __forceinline__ void run(float (&c)[64], int lane){}
};

// ---------------- prep ----------------
__global__ void prep_kernel(const float* __restrict__ Cm, const float* __restrict__ dm,
                            const float* __restrict__ r_diag,
                            float* __restrict__ crvT, float* __restrict__ ccT,
                            float* __restrict__ cd, float* __restrict__ rinv){
  __shared__ float s_crv[NNEU*NF];
  __shared__ float s_cm[NNEU*NF];
  __shared__ float s_dm[NNEU];
  int tid = threadIdx.x;            // 512; thread == neuron n
  float ri = 1.0f / r_diag[tid];
  rinv[tid] = ri;
  s_dm[tid] = dm[tid];
  #pragma unroll
  for (int f = 0; f < NF; ++f){
    float cv = Cm[tid*NF + f];
    s_cm[tid*NF + f] = cv;
    float v = cv * ri;
    s_crv[tid*NF + f] = v;
    crvT[tid*NF + f] = v;
  }
  __syncthreads();
  if (tid < 64){
    int f = tid >> 3, g = tid & 7;
    float acc = 0.f;
    for (int n = 0; n < NNEU; ++n) acc += s_crv[n*NF+f] * s_cm[n*NF+g];
    ccT[tid] = acc;
  } else if (tid < 72){
    int f = tid - 64;
    float acc = 0.f;
    for (int n = 0; n < NNEU; ++n) acc += s_crv[n*NF+f] * s_dm[n];
    cd[f] = acc;
  }
}

// ---------------- 8x8 eig: cyclic Jacobi, wave-parallel, fp32 ----------------
__global__ void eig8_kernel(const float* __restrict__ ccT,
                            float* __restrict__ Vf, float* __restrict__ lam){
  int lane = threadIdx.x & 63;      // one wave, 64 lanes
  int a = lane >> 3, b = lane & 7;
  float Av = ccT[lane];
  float Vv = (a == b) ? 1.0f : 0.0f;
  for (int sw = 0; sw < 8; ++sw){
    for (int p = 0; p < 7; ++p){
      for (int q = p + 1; q < 8; ++q){
        float apq = __shfl(Av, p*8 + q, 64);
        if (fabsf(apq) < 1e-20f) continue;          // uniform: apq is wave-broadcast
        float app = __shfl(Av, p*8 + p, 64);
        float aqq = __shfl(Av, q*8 + q, 64);
        float beta = (aqq - app) / (2.0f * apq);
        float tt = ((beta >= 0.0f) ? 1.0f : -1.0f) / (fabsf(beta) + sqrtf(1.0f + beta*beta));
        float c = 1.0f / sqrtf(1.0f + tt*tt);
        float s = tt * c;
        int bp = (b == p) ? q : (b == q) ? p : b;   // partner column
        float Ac = __shfl(Av, a*8 + bp, 64);        // snapshot before writes
        float Vc = __shfl(Vv, a*8 + bp, 64);
        if (b == p)      { Av = c*Av - s*Ac;  Vv = c*Vv - s*Vc; }
        else if (b == q) { Av = s*Ac + c*Av;  Vv = s*Vc + c*Vv; }
        int ap = (a == p) ? q : (a == q) ? p : a;   // partner row
        float Ar = __shfl(Av, ap*8 + b, 64);
        if (a == p)      Av = c*Av - s*Ar;
        else if (a == q) Av = s*Ar + c*Av;
      }
    }
  }
  if (a == b) lam[a] = Av;
  Vf[lane] = Vv;
}

// ---------------- rotate crv, cd by V^T ----------------
__global__ void rotv_kernel(const float* __restrict__ crvT, const float* __restrict__ cd,
                            const float* __restrict__ Vf,
                            float* __restrict__ crvVT, float* __restrict__ cdV){
  __shared__ float Vl[64];
  int tid = threadIdx.x;   // 512
  if (tid < 64) Vl[tid] = Vf[tid];
  __syncthreads();
  float cv[8], ov[8];
  load8(cv, crvT + tid*8);
  #pragma unroll
  for (int i = 0; i < 8; ++i){
    float s = 0.f;
    #pragma unroll
    for (int f = 0; f < 8; ++f) s += Vl[f*8+i] * cv[f];
    ov[i] = s;
  }
  store8(crvVT + tid*8, ov);
  if (tid < 8){
    float s = 0.f;
    #pragma unroll
    for (int f = 0; f < 8; ++f) s += Vl[f*8+tid] * cd[f];
    cdV[tid] = s;
  }
}

// ---------------- build K_f (fp32) ----------------
__global__ void buildK_kernel(const float* __restrict__ gamma, float* __restrict__ A0){
  int f = blockIdx.y;
  int idx = blockIdx.x*256 + threadIdx.x;   // t*512+u
  int t = idx >> 9, u = idx & 511;
  float g = gamma[f];
  float d = (float)(t - u);
  float v = 0.999f * expf(-0.5f * g * d * d);
  if (t == u) v += 1.0e-3f;
  A0[(size_t)f*TBINS*TBINS + idx] = v;
}

// ---------------- G_i = (sum_f Kinv_f) + lam_i I ----------------
__global__ void buildG_kernel(const float* __restrict__ A0, const float* __restrict__ lam,
                              float* __restrict__ A1){
  int idx = blockIdx.x*256 + threadIdx.x;       // 0..262143
  float s = 0.f;
  #pragma unroll
  for (int f2 = 0; f2 < NF; ++f2) s += A0[(size_t)f2*TBINS*TBINS + idx];
  bool diag = ((idx >> 9) == (idx & 511));
  #pragma unroll
  for (int i = 0; i < NF; ++i)
    A1[(size_t)i*TBINS*TBINS + idx] = s + (diag ? lam[i] : 0.f);
}

// ---------------- standalone pivot inversion (chain head): Pout = inv(A[f][0:64][0:64]) ----------------
__global__ __launch_bounds__(64) void gj_pivot0(const float* __restrict__ A,
                                                float* __restrict__ Pout){
  int f = blockIdx.x;
  int lane = threadIdx.x;           // 64
  const float* Af = A + (size_t)f*TBINS*TBINS;
  float c[64];
  #pragma unroll
  for (int i = 0; i < 64; ++i) c[i] = Af[(size_t)i*TBINS + lane];   // coalesced per i
  GJChain<0>::run(c, lane);
  #pragma unroll
  for (int i = 0; i < 64; ++i) Pout[f*4096 + i*64 + lane] = c[i];   // coalesced per i
}

// ---------------- GJ apply step: src -> dst; pivot inverse from Pin; designated
// block (k+1,k+1) also inverts its output tile -> Pout ----------------
#define ACC4(tm, fm) \
  tm[0] += fm.x*s0.x + fm.y*s1.x + fm.z*s2.x + fm.w*s3.x; \
  tm[1] += fm.x*s0.y + fm.y*s1.y + fm.z*s2.y + fm.w*s3.y; \
  tm[2] += fm.x*s0.z + fm.y*s1.z + fm.z*s2.z + fm.w*s3.z; \
  tm[3] += fm.x*s0.w + fm.y*s1.w + fm.z*s2.w + fm.w*s3.w;

__global__ __launch_bounds__(256) void gj_apply(const float* __restrict__ src,
                                                float* __restrict__ dst,
                                                const float* __restrict__ Pin,
                                                float* __restrict__ Pout,
                                                int k, int inv_next){
  __shared__ float P[64*PAD];
  __shared__ float Q[64*PAD];
  __shared__ float F[64*PAD];
  int f  = blockIdx.y;
  int ti = blockIdx.x >> 3, tj = blockIdx.x & 7;
  int tid = threadIdx.x;
  const float* A = src + (size_t)f*TBINS*TBINS;
  float* D = dst + (size_t)f*TBINS*TBINS;

  // load pivot inverse (precomputed)
  for (int v = tid; v < 1024; v += 256){
    int r = v >> 4, c4 = (v & 15) << 2;
    *(float4*)&P[r*PAD + c4] = *(const float4*)(Pin + f*4096 + r*64 + c4);
  }
  if (tj != k){
    for (int v = tid; v < 1024; v += 256){
      int r = v >> 4, c4 = (v & 15) << 2;
      *(float4*)&Q[r*PAD + c4] = *(const float4*)(A + (size_t)(k*64+r)*TBINS + tj*64 + c4);
    }
  }
  if (ti != k){
    for (int v = tid; v < 1024; v += 256){
      int r = v >> 4, c4 = (v & 15) << 2;
      *(float4*)&F[r*PAD + c4] = *(const float4*)(A + (size_t)(ti*64+r)*TBINS + k*64 + c4);
    }
  }
  __syncthreads();

  int jg = (tid & 15) << 2;   // output cols jg..jg+3
  int ib = (tid >> 4) << 2;   // output rows ib..ib+3

  if (tj == k){
    if (ti == k){
      // pass-through: D[k][k] = P
      for (int v = tid; v < 1024; v += 256){
        int r = v >> 4, c4 = (v & 15) << 2;
        *(float4*)(D + (size_t)(k*64+r)*TBINS + k*64 + c4) = *(float4*)&P[r*PAD + c4];
      }
      return;
    }
    // D = -F @ P
    float w[4][4] = {{0.f,0.f,0.f,0.f},{0.f,0.f,0.f,0.f},{0.f,0.f,0.f,0.f},{0.f,0.f,0.f,0.f}};
    for (int u4 = 0; u4 < 64; u4 += 4){
      float4 f0 = *(float4*)&F[(ib+0)*PAD + u4];
      float4 f1 = *(float4*)&F[(ib+1)*PAD + u4];
      float4 f2 = *(float4*)&F[(ib+2)*PAD + u4];
      float4 f3 = *(float4*)&F[(ib+3)*PAD + u4];
      float4 s0 = *(float4*)&P[(u4+0)*PAD + jg];
      float4 s1 = *(float4*)&P[(u4+1)*PAD + jg];
      float4 s2 = *(float4*)&P[(u4+2)*PAD + jg];
      float4 s3 = *(float4*)&P[(u4+3)*PAD + jg];
      ACC4(w[0], f0); ACC4(w[1], f1); ACC4(w[2], f2); ACC4(w[3], f3);
    }
    #pragma unroll
    for (int m = 0; m < 4; ++m)
      *(float4*)(D + (size_t)(ti*64+ib+m)*TBINS + k*64 + jg)
        = make_float4(-w[m][0], -w[m][1], -w[m][2], -w[m][3]);
    return;
  }

  // tj != k: T = P @ Q (P symmetric: P'[ib][u] = P[u][ib])
  float t[4][4] = {{0.f,0.f,0.f,0.f},{0.f,0.f,0.f,0.f},{0.f,0.f,0.f,0.f},{0.f,0.f,0.f,0.f}};
  for (int u = 0; u < 64; ++u){
    float4 pv = *(float4*)&P[u*PAD + ib];
    float4 qv = *(float4*)&Q[u*PAD + jg];
    t[0][0]+=pv.x*qv.x; t[0][1]+=pv.x*qv.y; t[0][2]+=pv.x*qv.z; t[0][3]+=pv.x*qv.w;
    t[1][0]+=pv.y*qv.x; t[1][1]+=pv.y*qv.y; t[1][2]+=pv.y*qv.z; t[1][3]+=pv.y*qv.w;
    t[2][0]+=pv.z*qv.x; t[2][1]+=pv.z*qv.y; t[2][2]+=pv.z*qv.z; t[2][3]+=pv.z*qv.w;
    t[3][0]+=pv.w*qv.x; t[3][1]+=pv.w*qv.y; t[3][2]+=pv.w*qv.z; t[3][3]+=pv.w*qv.w;
  }
  if (ti == k){
    // D = T directly from registers
    #pragma unroll
    for (int m = 0; m < 4; ++m)
      *(float4*)(D + (size_t)(k*64+ib+m)*TBINS + tj*64 + jg)
        = make_float4(t[m][0],t[m][1],t[m][2],t[m][3]);
    return;
  }
  __syncthreads();               // all reads of Q done
  #pragma unroll
  for (int m = 0; m < 4; ++m)
    *(float4*)&Q[(ib+m)*PAD + jg] = make_float4(t[m][0],t[m][1],t[m][2],t[m][3]);
  __syncthreads();               // T visible to all

  // Schur: D = A[ti][tj] - F @ T
  float w[4][4] = {{0.f,0.f,0.f,0.f},{0.f,0.f,0.f,0.f},{0.f,0.f,0.f,0.f},{0.f,0.f,0.f,0.f}};
  for (int u4 = 0; u4 < 64; u4 += 4){
    float4 f0 = *(float4*)&F[(ib+0)*PAD + u4];
    float4 f1 = *(float4*)&F[(ib+1)*PAD + u4];
    float4 f2 = *(float4*)&F[(ib+2)*PAD + u4];
    float4 f3 = *(float4*)&F[(ib+3)*PAD + u4];
    float4 s0 = *(float4*)&Q[(u4+0)*PAD + jg];
    float4 s1 = *(float4*)&Q[(u4+1)*PAD + jg];
    float4 s2 = *(float4*)&Q[(u4+2)*PAD + jg];
    float4 s3 = *(float4*)&Q[(u4+3)*PAD + jg];
    ACC4(w[0], f0); ACC4(w[1], f1); ACC4(w[2], f2); ACC4(w[3], f3);
  }
  #pragma unroll
  for (int m = 0; m < 4; ++m){
    float4 av = *(const float4*)(A + (size_t)(ti*64+ib+m)*TBINS + tj*64 + jg);
    float4 dv = make_float4(av.x - w[m][0], av.y - w[m][1], av.z - w[m][2], av.w - w[m][3]);
    *(float4*)(D + (size_t)(ti*64+ib+m)*TBINS + tj*64 + jg) = dv;
    w[m][0] = dv.x; w[m][1] = dv.y; w[m][2] = dv.z; w[m][3] = dv.w;
  }

  // designated block: next step's pivot inverse via single-wave register GJ
  if (inv_next && ti == k+1 && tj == k+1){
    __syncthreads();
    #pragma unroll
    for (int m = 0; m < 4; ++m)
      *(float4*)&P[(ib+m)*PAD + jg] = make_float4(w[m][0],w[m][1],w[m][2],w[m][3]);
    __syncthreads();
    if (tid < 64){
      float c[64];
      #pragma unroll
      for (int i = 0; i < 64; ++i) c[i] = P[i*PAD + tid];   // lane=column
      GJChain<0>::run(c, tid);
      #pragma unroll
      for (int i = 0; i < 64; ++i) Pout[f*4096 + i*64 + tid] = c[i];
    }
  }
}

// ---------------- term1 (chunked): btp[z][(t*8+i)*128+c] = sum_{n in chunk z} crvV[i][n] spike[c][n][t]
// grid (32 t-tiles, 8 c-tiles, 4 n-chunks); partials in dead A0; -cdV applied in reduce.
__global__ void term1_kernel(const float* __restrict__ spike, const float* __restrict__ crvVT,
                             float* __restrict__ btp){
  __shared__ float crl[128*NF];    // this chunk's [n][i]
  __shared__ float ot[128][17];
  int t0 = blockIdx.x * 16;
  int c0 = blockIdx.y * 16;
  int n0 = blockIdx.z << 7;        // 128-neuron chunk
  int tid = threadIdx.x;           // 256
  int tl = tid & 15, cl = tid >> 4;
  ((float4*)crl)[tid] = ((const float4*)(crvVT + n0*NF))[tid];   // 1024 floats
  __syncthreads();
  float acc[8] = {0.f,0.f,0.f,0.f,0.f,0.f,0.f,0.f};
  const float* Sp = spike + (size_t)(c0+cl)*NNEU*TBINS + (size_t)n0*TBINS + t0 + tl;
  for (int n = 0; n < 128; n += 8){
    float s[8];
    #pragma unroll
    for (int j = 0; j < 8; ++j) s[j] = Sp[(size_t)(n+j)*TBINS];   // 8 loads in flight
    #pragma unroll
    for (int j = 0; j < 8; ++j){
      float4 ca = *(float4*)&crl[(n+j)*8];
      float4 cb = *(float4*)&crl[(n+j)*8+4];
      acc[0] += ca.x*s[j]; acc[1] += ca.y*s[j]; acc[2] += ca.z*s[j]; acc[3] += ca.w*s[j];
      acc[4] += cb.x*s[j]; acc[5] += cb.y*s[j]; acc[6] += cb.z*s[j]; acc[7] += cb.w*s[j];
    }
  }
  #pragma unroll
  for (int i = 0; i < 8; ++i) ot[tl*8+i][cl] = acc[i];
  __syncthreads();
  int row = tid >> 1, off = (tid & 1) * 8;    // row = tlocal*8+i
  int tt = t0 + (row >> 3), ii = row & 7;
  float* dst = btp + (size_t)blockIdx.z*524288 + (size_t)(tt*8+ii)*NTRI + c0 + off;
  #pragma unroll
  for (int k = 0; k < 8; ++k) dst[k] = ot[row][off+k];
}

// ---------------- term1 reduce: bt = sum_z btp[z] - cdV[i] ----------------
__global__ void term1_reduce(const float* __restrict__ btp, const float* __restrict__ cdV,
                             float* __restrict__ bt){
  int idx = blockIdx.x*256 + threadIdx.x;   // float4 index, 131072 total
  const float4* p = (const float4*)btp;
  float4 a = p[idx];
  float4 b = p[idx + 131072];
  float4 c = p[idx + 262144];
  float4 d = p[idx + 393216];
  float cv = cdV[(idx >> 5) & 7];           // i = ((t*8+i)*32 + c4)>>5 & 7
  ((float4*)bt)[idx] = make_float4(a.x+b.x+c.x+d.x - cv,
                                   a.y+b.y+c.y+d.y - cv,
                                   a.z+b.z+c.z+d.z - cv,
                                   a.w+b.w+c.w+d.w - cv);
}

// ---------------- batched GEMM: xt_i = H_i (512x512) @ bt_i (512x128) ----------------
__global__ void gemm_kernel(const float* __restrict__ H, const float* __restrict__ bt,
                            float* __restrict__ xt){
  __shared__ float Ht[32][68];
  __shared__ float Bt[64][128];
  int i  = blockIdx.y;
  int t0 = blockIdx.x * 32;
  int tid = threadIdx.x;           // 256
  int gt = tid >> 5;               // 0..7
  int gc = tid & 31;               // 0..31
  float acc[4][4] = {{0.f,0.f,0.f,0.f},{0.f,0.f,0.f,0.f},{0.f,0.f,0.f,0.f},{0.f,0.f,0.f,0.f}};
  const float* Hi = H + (size_t)i*TBINS*TBINS;
  for (int uc = 0; uc < 8; ++uc){
    int u0 = uc*64;
    __syncthreads();
    for (int v = tid; v < 512; v += 256){
      int r = v >> 4, c4 = (v & 15) << 2;
      *(float4*)&Ht[r][c4] = *(const float4*)(Hi + (size_t)(t0+r)*TBINS + u0 + c4);
    }
    for (int v = tid; v < 2048; v += 256){
      int r = v >> 5, c4 = (v & 31) << 2;
      *(float4*)&Bt[r][c4] = *(const float4*)(bt + (size_t)((u0+r)*8 + i)*NTRI + c4);
    }
    __syncthreads();
    for (int u = 0; u < 64; ++u){
      float h0 = Ht[gt*4+0][u], h1 = Ht[gt*4+1][u], h2 = Ht[gt*4+2][u], h3 = Ht[gt*4+3][u];
      float b0 = Bt[u][gc], b1 = Bt[u][gc+32], b2 = Bt[u][gc+64], b3 = Bt[u][gc+96];
      acc[0][0] += h0*b0; acc[0][1] += h0*b1; acc[0][2] += h0*b2; acc[0][3] += h0*b3;
      acc[1][0] += h1*b0; acc[1][1] += h1*b1; acc[1][2] += h1*b2; acc[1][3] += h1*b3;
      acc[2][0] += h2*b0; acc[2][1] += h2*b1; acc[2][2] += h2*b2; acc[2][3] += h2*b3;
      acc[3][0] += h3*b0; acc[3][1] += h3*b1; acc[3][2] += h3*b2; acc[3][3] += h3*b3;
    }
  }
  #pragma unroll
  for (int m = 0; m < 4; ++m)
    #pragma unroll
    for (int j = 0; j < 4; ++j)
      xt[(size_t)((t0 + gt*4 + m)*8 + i)*NTRI + gc + 32*j] = acc[m][j];
}

// ---------------- output: out[c][f][t] = sum_i V[f][i] xt[(t*8+i)*128+c] ----------------
__global__ void output_kernel(const float* __restrict__ xt, const float* __restrict__ Vf,
                              float* __restrict__ out){
  __shared__ float T[128][68];
  __shared__ float Vl[64];
  int t0 = blockIdx.x * 64, c0 = blockIdx.y * 16;
  int tid = threadIdx.x;   // 256
  if (tid < 64) Vl[tid] = Vf[tid];
  __syncthreads();
  for (int idx = tid; idx < 1024; idx += 256){
    int tl = idx >> 4, cl = idx & 15;
    float xv[8];
    #pragma unroll
    for (int i = 0; i < 8; ++i)
      xv[i] = xt[(size_t)((t0+tl)*8+i)*NTRI + c0 + cl];
    #pragma unroll
    for (int f = 0; f < 8; ++f){
      float s = 0.f;
      #pragma unroll
      for (int i = 0; i < 8; ++i) s += Vl[f*8+i] * xv[i];
      T[cl*8+f][tl] = s;
    }
  }
  __syncthreads();
  int row = tid >> 1, half = tid & 1;   // row = cl*8+f
  int cc = c0 + (row >> 3), ff = row & 7;
  float* dst = out + (size_t)cc*NF*TBINS + ff*TBINS + t0 + half*32;
  #pragma unroll
  for (int k = 0; k < 8; ++k)
    ((float4*)dst)[k] = *(float4*)&T[row][half*32 + k*4];
}

extern "C" void kernel_launch(void* const* d_in, const int* in_sizes, int n_in,
                              void* d_out, int out_size, void* d_ws, size_t ws_size,
                              hipStream_t stream) {
  const float* spike  = (const float*)d_in[0];
  const float* Cm     = (const float*)d_in[1];
  const float* dm     = (const float*)d_in[2];
  const float* r_diag = (const float*)d_in[3];
  const float* gamma  = (const float*)d_in[4];
  float* out = (float*)d_out;
  float* ws = (float*)d_ws;

  float*  A0    = ws + OFF_A0;
  float*  A1    = ws + OFF_A1;
  float*  crvT  = ws + OFF_CRVT;
  float*  crvVT = ws + OFF_CRVVT;
  float*  ccT   = ws + OFF_CCT;
  float*  cd    = ws + OFF_CD;
  float*  cdV   = ws + OFF_CDV;
  float*  rinv  = ws + OFF_RINV;
  float*  lam   = ws + OFF_LAM;
  float*  Vf    = ws + OFF_VF;
  float*  bt    = ws + OFF_BT;
  float*  xt    = ws + OFF_XT;
  float*  Pb[2] = { ws + OFF_PP0, ws + OFF_PP1 };

  prep_kernel<<<1, 512, 0, stream>>>(Cm, dm, r_diag, crvT, ccT, cd, rinv);
  eig8_kernel<<<1, 64, 0, stream>>>(ccT, Vf, lam);
  rotv_kernel<<<1, 512, 0, stream>>>(crvT, cd, Vf, crvVT, cdV);
  buildK_kernel<<<dim3(1024, 8), 256, 0, stream>>>(gamma, A0);

  // chain 1: invert K_f (ping-pong A0 <-> A1, 8 steps -> result in A0)
  gj_pivot0<<<8, 64, 0, stream>>>(A0, Pb[0]);
  {
    float* s = A0; float* d = A1;
    for (int k = 0; k < 8; ++k){
      gj_apply<<<dim3(64, 8), 256, 0, stream>>>(s, d, Pb[k&1], Pb[(k+1)&1], k, (k < 7) ? 1 : 0);
      float* tmp = s; s = d; d = tmp;
    }
  }
  buildG_kernel<<<1024, 256, 0, stream>>>(A0, lam, A1);
  // chain 2: invert G_i (start A1, 8 steps -> H in A1; A0 dead afterwards)
  gj_pivot0<<<8, 64, 0, stream>>>(A1, Pb[0]);
  {
    float* s = A1; float* d = A0;
    for (int k = 0; k < 8; ++k){
      gj_apply<<<dim3(64, 8), 256, 0, stream>>>(s, d, Pb[k&1], Pb[(k+1)&1], k, (k < 7) ? 1 : 0);
      float* tmp = s; s = d; d = tmp;
    }
  }
  term1_kernel<<<dim3(32, 8, 4), 256, 0, stream>>>(spike, crvVT, A0);
  term1_reduce<<<512, 256, 0, stream>>>(A0, cdV, bt);
  gemm_kernel<<<dim3(16, 8), 256, 0, stream>>>(A1, bt, xt);
  output_kernel<<<dim3(8, 8), 256, 0, stream>>>(xt, Vf, out);
}